// Round 1
// baseline (1793.798 us; speedup 1.0000x reference)
//
#include <hip/hip_runtime.h>
#include <cstdint>
#include <cstddef>

// ---------------- problem constants ----------------
#define NN      100000
#define EE      1600000
#define GG      512
#define F_IN    64
#define DH      128
#define DHL     256
#define NC      128
#define FPD     6144
#define RD      6656        // DH+DH+DHL+FPD
#define RH      3328        // RD/2

static constexpr float BN_SCALE = 0.9999950000374997f; // 1/sqrt(1+1e-5)

// scan geometry
#define NB_SCAN 98          // ceil(100000/1024)
#define NP_PAD  (NB_SCAN*1024)  // 100352

// ---------------- CSR build ----------------
__global__ void k_deg(const int* __restrict__ dst, int* __restrict__ deg, int n)
{
    int i = blockIdx.x * 256 + threadIdx.x;
    if (i < n) atomicAdd(&deg[dst[i]], 1);
}

__global__ void k_gptr(const int* __restrict__ batch, int* __restrict__ gptr, int n)
{
    int i = blockIdx.x * 256 + threadIdx.x;
    if (i > n) return;
    if (i == 0) {
        int b0 = batch[0];
        for (int g = 0; g <= b0; ++g) gptr[g] = 0;
    } else if (i == n) {
        int bl = batch[n - 1];
        for (int g = bl + 1; g <= GG; ++g) gptr[g] = n;
    } else {
        int bp = batch[i - 1], bc = batch[i];
        for (int g = bp + 1; g <= bc; ++g) gptr[g] = i;
    }
}

__global__ __launch_bounds__(256) void k_scan1(const int* __restrict__ deg, int* __restrict__ bsum)
{
    __shared__ int sm[256];
    int base = blockIdx.x * 1024 + threadIdx.x * 4;
    int4 v = *(const int4*)(deg + base);
    sm[threadIdx.x] = v.x + v.y + v.z + v.w;
    __syncthreads();
    for (int off = 128; off > 0; off >>= 1) {
        if (threadIdx.x < off) sm[threadIdx.x] += sm[threadIdx.x + off];
        __syncthreads();
    }
    if (threadIdx.x == 0) bsum[blockIdx.x] = sm[0];
}

__global__ void k_scan2(const int* __restrict__ bsum, int* __restrict__ boff, int nb)
{
    if (threadIdx.x == 0) {
        int s = 0;
        for (int i = 0; i < nb; ++i) { boff[i] = s; s += bsum[i]; }
    }
}

__global__ __launch_bounds__(256) void k_scan3(const int* __restrict__ deg, const int* __restrict__ boff,
                                               int* __restrict__ ptr, int* __restrict__ cursor, int n)
{
    __shared__ int sm[256];
    int tid = threadIdx.x;
    int base = blockIdx.x * 1024 + tid * 4;
    int4 v = *(const int4*)(deg + base);
    int t = v.x + v.y + v.z + v.w;
    sm[tid] = t;
    __syncthreads();
    for (int off = 1; off < 256; off <<= 1) {
        int add = (tid >= off) ? sm[tid - off] : 0;
        __syncthreads();
        sm[tid] += add;
        __syncthreads();
    }
    int ex = boff[blockIdx.x] + sm[tid] - t;
    int pr0 = ex, pr1 = ex + v.x, pr2 = pr1 + v.y, pr3 = pr2 + v.z;
    int prs[4] = {pr0, pr1, pr2, pr3};
    for (int j = 0; j < 4; ++j) {
        int idx = base + j;
        if (idx <= n) {
            ptr[idx] = prs[j];
            if (idx < n) cursor[idx] = prs[j];
        }
    }
}

__global__ void k_place(const int* __restrict__ src, const int* __restrict__ dst,
                        int* __restrict__ cursor, int* __restrict__ csr, int n)
{
    int i = blockIdx.x * 256 + threadIdx.x;
    if (i < n) {
        int d = dst[i];
        int p = atomicAdd(&cursor[d], 1);
        csr[p] = src[i];
    }
}

// ---------------- aggregation: out[n] = x[n] + sum_{e in-edges} x[src[e]] ----------------
template<int D>
__global__ __launch_bounds__(256) void k_aggr(const float* __restrict__ X,
                                              const int* __restrict__ ptr,
                                              const int* __restrict__ csr,
                                              float* __restrict__ out, int n_nodes)
{
    constexpr int SLOTS = D / 4;
    constexpr int NPB = 256 / SLOTS;
    int slot = threadIdx.x % SLOTS;
    int ln = threadIdx.x / SLOTS;
    int n = blockIdx.x * NPB + ln;
    if (n >= n_nodes) return;
    const float4* Xv = (const float4*)X;
    float4 acc = Xv[(size_t)n * SLOTS + slot];
    int e0 = ptr[n], e1 = ptr[n + 1];
    for (int e = e0; e < e1; ++e) {
        int s = csr[e];
        float4 v = Xv[(size_t)s * SLOTS + slot];
        acc.x += v.x; acc.y += v.y; acc.z += v.z; acc.w += v.w;
    }
    ((float4*)out)[(size_t)n * SLOTS + slot] = acc;
}

// ---------------- fused GEMM + bias (+BN) (+ReLU) ----------------
// C[M,NOUT] = act((A @ W + bias) [* bn_g*BN_SCALE + bn_b])
// A is [M,K] (if ASPLIT>0: cols [0,ASPLIT) from A stride ASPLIT, rest from A2 stride K-ASPLIT)
template<int K, bool BN, bool RELU, int ASPLIT>
__global__ __launch_bounds__(256) void k_gemm(
    const float* __restrict__ A, const float* __restrict__ A2,
    const float* __restrict__ W, const float* __restrict__ bias,
    const float* __restrict__ bng, const float* __restrict__ bnb,
    float* __restrict__ C, int M, int NOUT)
{
    constexpr int TS = 64, KT = 16;
    __shared__ float As[KT][TS];
    __shared__ float Ws[KT][TS];
    const int tid = threadIdx.x;
    const int tx = tid & 15, ty = tid >> 4;
    const int row0 = blockIdx.x * TS, col0 = blockIdx.y * TS;
    float acc[4][4] = {};
    const int a_r = tid >> 2;
    const int a_k = (tid & 3) * 4;
    const int w_k = tid >> 4;
    const int w_c = (tid & 15) * 4;
    const int ar = row0 + a_r;

    for (int k0 = 0; k0 < K; k0 += KT) {
        float4 av = make_float4(0.f, 0.f, 0.f, 0.f);
        if (ar < M) {
            int kg = k0 + a_k;
            if constexpr (ASPLIT > 0) {
                if (kg >= ASPLIT)
                    av = *(const float4*)(A2 + (size_t)ar * (K - ASPLIT) + (kg - ASPLIT));
                else
                    av = *(const float4*)(A + (size_t)ar * ASPLIT + kg);
            } else {
                av = *(const float4*)(A + (size_t)ar * K + kg);
            }
        }
        As[a_k + 0][a_r] = av.x;
        As[a_k + 1][a_r] = av.y;
        As[a_k + 2][a_r] = av.z;
        As[a_k + 3][a_r] = av.w;
        *(float4*)&Ws[w_k][w_c] = *(const float4*)(W + (size_t)(k0 + w_k) * NOUT + col0 + w_c);
        __syncthreads();
#pragma unroll
        for (int kk = 0; kk < KT; ++kk) {
            const float4 a4 = *(const float4*)&As[kk][ty * 4];
            const float4 w4 = *(const float4*)&Ws[kk][tx * 4];
            float a[4] = {a4.x, a4.y, a4.z, a4.w};
            float w[4] = {w4.x, w4.y, w4.z, w4.w};
#pragma unroll
            for (int i = 0; i < 4; ++i)
#pragma unroll
                for (int j = 0; j < 4; ++j)
                    acc[i][j] = fmaf(a[i], w[j], acc[i][j]);
        }
        __syncthreads();
    }

    const int col = col0 + tx * 4;
    float4 bi = *(const float4*)(bias + col);
    float4 sg = make_float4(1.f, 1.f, 1.f, 1.f), sb = make_float4(0.f, 0.f, 0.f, 0.f);
    if (BN) {
        sg = *(const float4*)(bng + col);
        sb = *(const float4*)(bnb + col);
    }
#pragma unroll
    for (int i = 0; i < 4; ++i) {
        int row = row0 + ty * 4 + i;
        if (row >= M) break;
        float o[4];
        o[0] = acc[i][0] + bi.x; o[1] = acc[i][1] + bi.y;
        o[2] = acc[i][2] + bi.z; o[3] = acc[i][3] + bi.w;
        if (BN) {
            o[0] = o[0] * (sg.x * BN_SCALE) + sb.x;
            o[1] = o[1] * (sg.y * BN_SCALE) + sb.y;
            o[2] = o[2] * (sg.z * BN_SCALE) + sb.z;
            o[3] = o[3] * (sg.w * BN_SCALE) + sb.w;
        }
        if (RELU) {
            o[0] = fmaxf(o[0], 0.f); o[1] = fmaxf(o[1], 0.f);
            o[2] = fmaxf(o[2], 0.f); o[3] = fmaxf(o[3], 0.f);
        }
        float4 ov = make_float4(o[0], o[1], o[2], o[3]);
        *(float4*)(C + (size_t)row * NOUT + col) = ov;
    }
}

// ---------------- split-K GEMM with atomic accumulate (for tiny out3) ----------------
template<int KC>
__global__ __launch_bounds__(256) void k_gemm_at(const float* __restrict__ A,
                                                 const float* __restrict__ W,
                                                 float* __restrict__ C,
                                                 int M, int NOUT, int K)
{
    constexpr int TS = 64, KT = 16;
    __shared__ float As[KT][TS];
    __shared__ float Ws[KT][TS];
    const int tid = threadIdx.x;
    const int tx = tid & 15, ty = tid >> 4;
    const int row0 = blockIdx.x * TS, col0 = blockIdx.y * TS;
    const int kbase = blockIdx.z * KC;
    float acc[4][4] = {};
    const int a_r = tid >> 2;
    const int a_k = (tid & 3) * 4;
    const int w_k = tid >> 4;
    const int w_c = (tid & 15) * 4;
    const int ar = row0 + a_r;

    for (int k0 = kbase; k0 < kbase + KC; k0 += KT) {
        float4 av = make_float4(0.f, 0.f, 0.f, 0.f);
        if (ar < M) av = *(const float4*)(A + (size_t)ar * K + k0 + a_k);
        As[a_k + 0][a_r] = av.x;
        As[a_k + 1][a_r] = av.y;
        As[a_k + 2][a_r] = av.z;
        As[a_k + 3][a_r] = av.w;
        *(float4*)&Ws[w_k][w_c] = *(const float4*)(W + (size_t)(k0 + w_k) * NOUT + col0 + w_c);
        __syncthreads();
#pragma unroll
        for (int kk = 0; kk < KT; ++kk) {
            const float4 a4 = *(const float4*)&As[kk][ty * 4];
            const float4 w4 = *(const float4*)&Ws[kk][tx * 4];
            float a[4] = {a4.x, a4.y, a4.z, a4.w};
            float w[4] = {w4.x, w4.y, w4.z, w4.w};
#pragma unroll
            for (int i = 0; i < 4; ++i)
#pragma unroll
                for (int j = 0; j < 4; ++j)
                    acc[i][j] = fmaf(a[i], w[j], acc[i][j]);
        }
        __syncthreads();
    }
#pragma unroll
    for (int i = 0; i < 4; ++i) {
        int row = row0 + ty * 4 + i;
        if (row >= M) continue;
#pragma unroll
        for (int j = 0; j < 4; ++j)
            atomicAdd(&C[(size_t)row * NOUT + col0 + tx * 4 + j], acc[i][j]);
    }
}

__global__ void k_init_out(const float* __restrict__ b, float* __restrict__ out)
{
    int i = blockIdx.x * 256 + threadIdx.x;   // 65536 total
    out[i] = b[i & (NC - 1)];
}

// ---------------- per-graph pooling (atomic, 8-way node split) ----------------
template<int D>
__global__ void k_pool(const float* __restrict__ H, const int* __restrict__ gptr,
                       float* __restrict__ pool512, int colOff)
{
    int g = blockIdx.x;
    int part = blockIdx.y;            // 0..7
    int f = threadIdx.x;              // blockDim = D
    int n0 = gptr[g], n1 = gptr[g + 1];
    float acc = 0.f;
    for (int n = n0 + part; n < n1; n += 8)
        acc += H[(size_t)n * D + f];
    atomicAdd(&pool512[(size_t)g * 512 + colOff + f], acc);
}

// ---------------- launch ----------------
extern "C" void kernel_launch(void* const* d_in, const int* in_sizes, int n_in,
                              void* d_out, int out_size, void* d_ws, size_t ws_size,
                              hipStream_t stream)
{
    const float* x     = (const float*)d_in[0];
    const int*   ei    = (const int*)d_in[1];
    const int*   src   = ei;
    const int*   dst   = ei + EE;
    const int*   batch = (const int*)d_in[2];
    const float* fp    = (const float*)d_in[3];
    const float* c1w1  = (const float*)d_in[4];
    const float* c1b1  = (const float*)d_in[5];
    const float* c1w2  = (const float*)d_in[6];
    const float* c1b2  = (const float*)d_in[7];
    const float* c2w1  = (const float*)d_in[8];
    const float* c2b1  = (const float*)d_in[9];
    const float* c2w2  = (const float*)d_in[10];
    const float* c2b2  = (const float*)d_in[11];
    const float* c3w1  = (const float*)d_in[12];
    const float* c3b1  = (const float*)d_in[13];
    const float* c3w2  = (const float*)d_in[14];
    const float* c3b2  = (const float*)d_in[15];
    const float* bn1g  = (const float*)d_in[16];
    const float* bn1b  = (const float*)d_in[17];
    const float* bn2g  = (const float*)d_in[18];
    const float* bn2b  = (const float*)d_in[19];
    const float* bn3g  = (const float*)d_in[20];
    const float* bn3b  = (const float*)d_in[21];
    const float* o1w   = (const float*)d_in[22];
    const float* o1b   = (const float*)d_in[23];
    const float* obng  = (const float*)d_in[24];
    const float* obnb  = (const float*)d_in[25];
    const float* o3w   = (const float*)d_in[26];
    const float* o3b   = (const float*)d_in[27];
    float* out = (float*)d_out;

    char* ws = (char*)d_ws;
    size_t off = 0;
    auto alloc = [&](size_t bytes) {
        size_t r = off;
        off = (off + bytes + 255) & ~(size_t)255;
        return r;
    };
    float* bufA    = (float*)(ws + alloc((size_t)NN * 256 * 4));
    float* bufB    = (float*)(ws + alloc((size_t)NN * 256 * 4));
    float* h1      = (float*)(ws + alloc((size_t)NN * DH * 4));
    float* h2      = (float*)(ws + alloc((size_t)NN * DH * 4));
    float* pool512 = (float*)(ws + alloc((size_t)GG * 512 * 4));
    float* hmid    = (float*)(ws + alloc((size_t)GG * RH * 4));
    int*   deg     = (int*)(ws + alloc((size_t)NP_PAD * 4));
    int*   ptr     = (int*)(ws + alloc((size_t)(NN + 1) * 4));
    int*   cursor  = (int*)(ws + alloc((size_t)NN * 4));
    int*   bsum    = (int*)(ws + alloc((size_t)NB_SCAN * 4));
    int*   boff    = (int*)(ws + alloc((size_t)NB_SCAN * 4));
    int*   gptr    = (int*)(ws + alloc((size_t)(GG + 1) * 4));
    int*   csr     = (int*)(ws + alloc((size_t)EE * 4));
    (void)ws_size; (void)in_sizes; (void)n_in; (void)out_size;

    // ---- CSR + graph boundaries ----
    hipMemsetAsync(deg, 0, (size_t)NP_PAD * 4, stream);
    hipMemsetAsync(pool512, 0, (size_t)GG * 512 * 4, stream);
    k_deg<<<(EE + 255) / 256, 256, 0, stream>>>(dst, deg, EE);
    k_gptr<<<(NN + 256) / 256, 256, 0, stream>>>(batch, gptr, NN);
    k_scan1<<<NB_SCAN, 256, 0, stream>>>(deg, bsum);
    k_scan2<<<1, 64, 0, stream>>>(bsum, boff, NB_SCAN);
    k_scan3<<<NB_SCAN, 256, 0, stream>>>(deg, boff, ptr, cursor, NN);
    k_place<<<(EE + 255) / 256, 256, 0, stream>>>(src, dst, cursor, csr, EE);

    const int MT = (NN + 63) / 64;  // 1563 row tiles

    // ---- conv1 ----
    k_aggr<64><<<(NN + 15) / 16, 256, 0, stream>>>(x, ptr, csr, bufA, NN);
    k_gemm<64, false, true, 0><<<dim3(MT, 2), 256, 0, stream>>>(bufA, nullptr, c1w1, c1b1, nullptr, nullptr, bufB, NN, DH);
    k_gemm<128, true, true, 0><<<dim3(MT, 2), 256, 0, stream>>>(bufB, nullptr, c1w2, c1b2, bn1g, bn1b, h1, NN, DH);
    k_pool<128><<<dim3(GG, 8), 128, 0, stream>>>(h1, gptr, pool512, 0);

    // ---- conv2 ----
    k_aggr<128><<<(NN + 7) / 8, 256, 0, stream>>>(h1, ptr, csr, bufA, NN);
    k_gemm<128, false, true, 0><<<dim3(MT, 2), 256, 0, stream>>>(bufA, nullptr, c2w1, c2b1, nullptr, nullptr, bufB, NN, DH);
    k_gemm<128, true, true, 0><<<dim3(MT, 2), 256, 0, stream>>>(bufB, nullptr, c2w2, c2b2, bn2g, bn2b, h2, NN, DH);
    k_pool<128><<<dim3(GG, 8), 128, 0, stream>>>(h2, gptr, pool512, DH);

    // ---- conv3 ---- (h3 lives in bufA after its aggr input is dead)
    k_aggr<128><<<(NN + 7) / 8, 256, 0, stream>>>(h2, ptr, csr, bufA, NN);
    k_gemm<128, false, true, 0><<<dim3(MT, 4), 256, 0, stream>>>(bufA, nullptr, c3w1, c3b1, nullptr, nullptr, bufB, NN, DHL);
    k_gemm<256, true, true, 0><<<dim3(MT, 4), 256, 0, stream>>>(bufB, nullptr, c3w2, c3b2, bn3g, bn3b, bufA, NN, DHL);
    k_pool<256><<<dim3(GG, 8), 256, 0, stream>>>(bufA, gptr, pool512, 2 * DH);

    // ---- head: hmid = relu(bn(concat(pool512, fp) @ o1w + o1b)) ----
    k_gemm<RD, true, true, 512><<<dim3(8, RH / 64), 256, 0, stream>>>(pool512, fp, o1w, o1b, obng, obnb, hmid, GG, RH);

    // ---- out = hmid @ o3w + o3b (split-K, atomic) ----
    k_init_out<<<(GG * NC) / 256, 256, 0, stream>>>(o3b, out);
    k_gemm_at<128><<<dim3(8, NC / 64, RH / 128), 256, 0, stream>>>(hmid, o3w, out, GG, NC, RH);
}

// Round 2
// 1266.111 us; speedup vs baseline: 1.4168x; 1.4168x over previous
//
#include <hip/hip_runtime.h>
#include <cstdint>
#include <cstddef>

// ---------------- problem constants ----------------
#define NN      100000
#define EE      1600000
#define GG      512
#define F_IN    64
#define DH      128
#define DHL     256
#define NC      128
#define FPD     6144
#define RD      6656        // DH+DH+DHL+FPD
#define RH      3328        // RD/2

static constexpr float BN_SCALE = 0.9999950000374997f; // 1/sqrt(1+1e-5)

// scan geometry
#define NB_SCAN 98          // ceil(100000/1024)
#define NP_PAD  (NB_SCAN*1024)  // 100352

typedef __attribute__((ext_vector_type(8))) short bf16x8;
typedef __attribute__((ext_vector_type(4))) float f32x4;
typedef unsigned int uint32;
typedef unsigned short ushort16_t;

__device__ __forceinline__ ushort f2bf(float f) {
    uint32 u = __float_as_uint(f);
    uint32 r = u + 0x7fffu + ((u >> 16) & 1u);
    return (ushort)(r >> 16);
}
__device__ __forceinline__ float bf2f(ushort h) {
    return __uint_as_float(((uint32)h) << 16);
}
__device__ __forceinline__ uint4 pack8(const ushort* s) {
    uint4 r;
    r.x = (uint32)s[0] | ((uint32)s[1] << 16);
    r.y = (uint32)s[2] | ((uint32)s[3] << 16);
    r.z = (uint32)s[4] | ((uint32)s[5] << 16);
    r.w = (uint32)s[6] | ((uint32)s[7] << 16);
    return r;
}

// ---------------- CSR build ----------------
__global__ void k_deg(const int* __restrict__ dst, int* __restrict__ deg, int n)
{
    int i = blockIdx.x * 256 + threadIdx.x;
    if (i < n) atomicAdd(&deg[dst[i]], 1);
}

__global__ void k_gptr(const int* __restrict__ batch, int* __restrict__ gptr, int n)
{
    int i = blockIdx.x * 256 + threadIdx.x;
    if (i > n) return;
    if (i == 0) {
        int b0 = batch[0];
        for (int g = 0; g <= b0; ++g) gptr[g] = 0;
    } else if (i == n) {
        int bl = batch[n - 1];
        for (int g = bl + 1; g <= GG; ++g) gptr[g] = n;
    } else {
        int bp = batch[i - 1], bc = batch[i];
        for (int g = bp + 1; g <= bc; ++g) gptr[g] = i;
    }
}

__global__ __launch_bounds__(256) void k_scan1(const int* __restrict__ deg, int* __restrict__ bsum)
{
    __shared__ int sm[256];
    int base = blockIdx.x * 1024 + threadIdx.x * 4;
    int4 v = *(const int4*)(deg + base);
    sm[threadIdx.x] = v.x + v.y + v.z + v.w;
    __syncthreads();
    for (int off = 128; off > 0; off >>= 1) {
        if (threadIdx.x < off) sm[threadIdx.x] += sm[threadIdx.x + off];
        __syncthreads();
    }
    if (threadIdx.x == 0) bsum[blockIdx.x] = sm[0];
}

__global__ void k_scan2(const int* __restrict__ bsum, int* __restrict__ boff, int nb)
{
    if (threadIdx.x == 0) {
        int s = 0;
        for (int i = 0; i < nb; ++i) { boff[i] = s; s += bsum[i]; }
    }
}

__global__ __launch_bounds__(256) void k_scan3(const int* __restrict__ deg, const int* __restrict__ boff,
                                               int* __restrict__ ptr, int* __restrict__ cursor, int n)
{
    __shared__ int sm[256];
    int tid = threadIdx.x;
    int base = blockIdx.x * 1024 + tid * 4;
    int4 v = *(const int4*)(deg + base);
    int t = v.x + v.y + v.z + v.w;
    sm[tid] = t;
    __syncthreads();
    for (int off = 1; off < 256; off <<= 1) {
        int add = (tid >= off) ? sm[tid - off] : 0;
        __syncthreads();
        sm[tid] += add;
        __syncthreads();
    }
    int ex = boff[blockIdx.x] + sm[tid] - t;
    int pr0 = ex, pr1 = ex + v.x, pr2 = pr1 + v.y, pr3 = pr2 + v.z;
    int prs[4] = {pr0, pr1, pr2, pr3};
    for (int j = 0; j < 4; ++j) {
        int idx = base + j;
        if (idx <= n) {
            ptr[idx] = prs[j];
            if (idx < n) cursor[idx] = prs[j];
        }
    }
}

__global__ void k_place(const int* __restrict__ src, const int* __restrict__ dst,
                        int* __restrict__ cursor, int* __restrict__ csr, int n)
{
    int i = blockIdx.x * 256 + threadIdx.x;
    if (i < n) {
        int d = dst[i];
        int p = atomicAdd(&cursor[d], 1);
        csr[p] = src[i];
    }
}

// ---------------- aggregation: out[n] = x[n] + sum_{e in-edges} x[src[e]] ----------------
template<int D>
__global__ __launch_bounds__(256) void k_aggr(const float* __restrict__ X,
                                              const int* __restrict__ ptr,
                                              const int* __restrict__ csr,
                                              float* __restrict__ out, int n_nodes)
{
    constexpr int SLOTS = D / 4;
    constexpr int NPB = 256 / SLOTS;
    int slot = threadIdx.x % SLOTS;
    int ln = threadIdx.x / SLOTS;
    int n = blockIdx.x * NPB + ln;
    if (n >= n_nodes) return;
    const float4* Xv = (const float4*)X;
    float4 acc = Xv[(size_t)n * SLOTS + slot];
    int e0 = ptr[n], e1 = ptr[n + 1];
    for (int e = e0; e < e1; ++e) {
        int s = csr[e];
        float4 v = Xv[(size_t)s * SLOTS + slot];
        acc.x += v.x; acc.y += v.y; acc.z += v.z; acc.w += v.w;
    }
    ((float4*)out)[(size_t)n * SLOTS + slot] = acc;
}

// ---------------- MFMA GEMM with hi/lo bf16 split (fp32-grade accuracy) ----------------
// C[M,NOUT] = epilogue(A @ W)   A:[M,KTOT] fp32 (ASPLIT concat), W:[KTOT,NOUT] fp32
// EPI=true : C = act((acc+bias)[*bn]) directly
// EPI=false: C is partial slab array, blockIdx.z picks K-chunk, raw acc stored
template<int KTOT, int KCHUNK, bool EPI, bool BNF, bool RELU, int ASPLIT>
__global__ __launch_bounds__(256, 2) void k_mgemm(
    const float* __restrict__ A, const float* __restrict__ A2,
    const float* __restrict__ W, const float* __restrict__ bias,
    const float* __restrict__ bng, const float* __restrict__ bnb,
    float* __restrict__ C, int M, int NOUT)
{
    __shared__ ushort Ah[128][40];
    __shared__ ushort Al[128][40];
    __shared__ ushort Bh[128][40];
    __shared__ ushort Bl[128][40];

    const int t = threadIdx.x;
    const int lane = t & 63, wid = t >> 6;
    const int wm = wid >> 1, wn = wid & 1;
    const int fr = lane & 15, fkq = lane >> 4;   // frag row/col, k-quarter
    const int row0 = blockIdx.x * 128, col0 = blockIdx.y * 128;
    const int kb = blockIdx.z * KCHUNK;

    const int arow = t >> 1, akh = t & 1;        // A-stage: row, k-half
    const int bcol = t & 127, bkh = t >> 7;      // B-stage: col, k-half
    const int agr = row0 + arow;

    f32x4 acc[4][4];
#pragma unroll
    for (int m = 0; m < 4; ++m)
#pragma unroll
        for (int n = 0; n < 4; ++n)
            acc[m][n] = (f32x4){0.f, 0.f, 0.f, 0.f};

    for (int k0 = 0; k0 < KCHUNK; k0 += 32) {
        // ---- stage A (128 x 32) ----
        float av[16];
        if (agr < M) {
#pragma unroll
            for (int j = 0; j < 4; ++j) {
                int kg = kb + k0 + akh * 16 + j * 4;
                float4 f;
                if constexpr (ASPLIT > 0) {
                    if (kg >= ASPLIT)
                        f = *(const float4*)(A2 + (size_t)agr * (KTOT - ASPLIT) + (kg - ASPLIT));
                    else
                        f = *(const float4*)(A + (size_t)agr * ASPLIT + kg);
                } else {
                    f = *(const float4*)(A + (size_t)agr * KTOT + kg);
                }
                av[j * 4 + 0] = f.x; av[j * 4 + 1] = f.y;
                av[j * 4 + 2] = f.z; av[j * 4 + 3] = f.w;
            }
        } else {
#pragma unroll
            for (int j = 0; j < 16; ++j) av[j] = 0.f;
        }
        ushort ahh[16], all_[16];
#pragma unroll
        for (int j = 0; j < 16; ++j) {
            ushort h = f2bf(av[j]);
            ahh[j] = h;
            all_[j] = f2bf(av[j] - bf2f(h));
        }
        *(uint4*)&Ah[arow][akh * 16] = pack8(ahh);
        *(uint4*)&Ah[arow][akh * 16 + 8] = pack8(ahh + 8);
        *(uint4*)&Al[arow][akh * 16] = pack8(all_);
        *(uint4*)&Al[arow][akh * 16 + 8] = pack8(all_ + 8);

        // ---- stage B (32 x 128), k-major in LDS ----
        float wv[16];
        const float* wp = W + (size_t)(kb + k0 + bkh * 16) * NOUT + col0 + bcol;
#pragma unroll
        for (int kk = 0; kk < 16; ++kk) wv[kk] = wp[(size_t)kk * NOUT];
        ushort bhh[16], bll[16];
#pragma unroll
        for (int j = 0; j < 16; ++j) {
            ushort h = f2bf(wv[j]);
            bhh[j] = h;
            bll[j] = f2bf(wv[j] - bf2f(h));
        }
        *(uint4*)&Bh[bcol][bkh * 16] = pack8(bhh);
        *(uint4*)&Bh[bcol][bkh * 16 + 8] = pack8(bhh + 8);
        *(uint4*)&Bl[bcol][bkh * 16] = pack8(bll);
        *(uint4*)&Bl[bcol][bkh * 16 + 8] = pack8(bll + 8);

        __syncthreads();

        // ---- compute ----
        bf16x8 fah[4], fal[4];
#pragma unroll
        for (int m = 0; m < 4; ++m) {
            fah[m] = *(const bf16x8*)&Ah[wm * 64 + m * 16 + fr][fkq * 8];
            fal[m] = *(const bf16x8*)&Al[wm * 64 + m * 16 + fr][fkq * 8];
        }
#pragma unroll
        for (int n = 0; n < 4; ++n) {
            bf16x8 fbh = *(const bf16x8*)&Bh[wn * 64 + n * 16 + fr][fkq * 8];
            bf16x8 fbl = *(const bf16x8*)&Bl[wn * 64 + n * 16 + fr][fkq * 8];
#pragma unroll
            for (int m = 0; m < 4; ++m) {
                acc[m][n] = __builtin_amdgcn_mfma_f32_16x16x32_bf16(fah[m], fbh, acc[m][n], 0, 0, 0);
                acc[m][n] = __builtin_amdgcn_mfma_f32_16x16x32_bf16(fal[m], fbh, acc[m][n], 0, 0, 0);
                acc[m][n] = __builtin_amdgcn_mfma_f32_16x16x32_bf16(fah[m], fbl, acc[m][n], 0, 0, 0);
            }
        }
        __syncthreads();
    }

    // ---- epilogue ----
    if constexpr (EPI) {
#pragma unroll
        for (int n = 0; n < 4; ++n) {
            int col = col0 + wn * 64 + n * 16 + fr;
            float bi = bias[col];
            float g = 1.f, bb = 0.f;
            if constexpr (BNF) { g = bng[col] * BN_SCALE; bb = bnb[col]; }
#pragma unroll
            for (int m = 0; m < 4; ++m) {
                int rbase = row0 + wm * 64 + m * 16 + fkq * 4;
#pragma unroll
                for (int r = 0; r < 4; ++r) {
                    int row = rbase + r;
                    if (row < M) {
                        float o = acc[m][n][r] + bi;
                        if constexpr (BNF) o = o * g + bb;
                        if constexpr (RELU) o = fmaxf(o, 0.f);
                        C[(size_t)row * NOUT + col] = o;
                    }
                }
            }
        }
    } else {
        float* P = C + (size_t)blockIdx.z * M * NOUT;
#pragma unroll
        for (int n = 0; n < 4; ++n) {
            int col = col0 + wn * 64 + n * 16 + fr;
#pragma unroll
            for (int m = 0; m < 4; ++m) {
                int rbase = row0 + wm * 64 + m * 16 + fkq * 4;
#pragma unroll
                for (int r = 0; r < 4; ++r) {
                    int row = rbase + r;
                    if (row < M) P[(size_t)row * NOUT + col] = acc[m][n][r];
                }
            }
        }
    }
}

// ---------------- split-K reductions ----------------
__global__ void k_red_head(const float* __restrict__ P, const float* __restrict__ bias,
                           const float* __restrict__ g, const float* __restrict__ b,
                           float* __restrict__ O)
{
    int i = blockIdx.x * 256 + threadIdx.x;     // 512*3328 total
    int col = i % RH;
    float s = 0.f;
#pragma unroll
    for (int z = 0; z < 8; ++z) s += P[(size_t)z * (GG * RH) + i];
    float o = (s + bias[col]) * (g[col] * BN_SCALE) + b[col];
    O[i] = fmaxf(o, 0.f);
}

__global__ void k_red_out(const float* __restrict__ P, const float* __restrict__ bias,
                          float* __restrict__ O)
{
    int i = blockIdx.x * 256 + threadIdx.x;     // 512*128 total
    float s = 0.f;
#pragma unroll
    for (int z = 0; z < 8; ++z) s += P[(size_t)z * (GG * NC) + i];
    O[i] = s + bias[i & (NC - 1)];
}

// ---------------- per-graph pooling (atomic, 8-way node split) ----------------
template<int D>
__global__ void k_pool(const float* __restrict__ H, const int* __restrict__ gptr,
                       float* __restrict__ pool512, int colOff)
{
    int g = blockIdx.x;
    int part = blockIdx.y;            // 0..7
    int f = threadIdx.x;              // blockDim = D
    int n0 = gptr[g], n1 = gptr[g + 1];
    float acc = 0.f;
    for (int n = n0 + part; n < n1; n += 8)
        acc += H[(size_t)n * D + f];
    atomicAdd(&pool512[(size_t)g * 512 + colOff + f], acc);
}

// ---------------- launch ----------------
extern "C" void kernel_launch(void* const* d_in, const int* in_sizes, int n_in,
                              void* d_out, int out_size, void* d_ws, size_t ws_size,
                              hipStream_t stream)
{
    const float* x     = (const float*)d_in[0];
    const int*   ei    = (const int*)d_in[1];
    const int*   src   = ei;
    const int*   dst   = ei + EE;
    const int*   batch = (const int*)d_in[2];
    const float* fp    = (const float*)d_in[3];
    const float* c1w1  = (const float*)d_in[4];
    const float* c1b1  = (const float*)d_in[5];
    const float* c1w2  = (const float*)d_in[6];
    const float* c1b2  = (const float*)d_in[7];
    const float* c2w1  = (const float*)d_in[8];
    const float* c2b1  = (const float*)d_in[9];
    const float* c2w2  = (const float*)d_in[10];
    const float* c2b2  = (const float*)d_in[11];
    const float* c3w1  = (const float*)d_in[12];
    const float* c3b1  = (const float*)d_in[13];
    const float* c3w2  = (const float*)d_in[14];
    const float* c3b2  = (const float*)d_in[15];
    const float* bn1g  = (const float*)d_in[16];
    const float* bn1b  = (const float*)d_in[17];
    const float* bn2g  = (const float*)d_in[18];
    const float* bn2b  = (const float*)d_in[19];
    const float* bn3g  = (const float*)d_in[20];
    const float* bn3b  = (const float*)d_in[21];
    const float* o1w   = (const float*)d_in[22];
    const float* o1b   = (const float*)d_in[23];
    const float* obng  = (const float*)d_in[24];
    const float* obnb  = (const float*)d_in[25];
    const float* o3w   = (const float*)d_in[26];
    const float* o3b   = (const float*)d_in[27];
    float* out = (float*)d_out;

    char* ws = (char*)d_ws;
    size_t off = 0;
    auto alloc = [&](size_t bytes) {
        size_t r = off;
        off = (off + bytes + 255) & ~(size_t)255;
        return r;
    };
    float* bufA    = (float*)(ws + alloc((size_t)NN * 256 * 4));
    float* bufB    = (float*)(ws + alloc((size_t)NN * 256 * 4));
    float* h1      = (float*)(ws + alloc((size_t)NN * DH * 4));
    float* h2      = (float*)(ws + alloc((size_t)NN * DH * 4));
    float* pool512 = (float*)(ws + alloc((size_t)GG * 512 * 4));
    float* hmid    = (float*)(ws + alloc((size_t)GG * RH * 4));
    int*   deg     = (int*)(ws + alloc((size_t)NP_PAD * 4));
    int*   ptr     = (int*)(ws + alloc((size_t)(NN + 1) * 4));
    int*   cursor  = (int*)(ws + alloc((size_t)NN * 4));
    int*   bsum    = (int*)(ws + alloc((size_t)NB_SCAN * 4));
    int*   boff    = (int*)(ws + alloc((size_t)NB_SCAN * 4));
    int*   gptr    = (int*)(ws + alloc((size_t)(GG + 1) * 4));
    int*   csr     = (int*)(ws + alloc((size_t)EE * 4));
    (void)ws_size; (void)in_sizes; (void)n_in; (void)out_size;

    // split-K partial slabs alias dead buffers:
    float* partH = bufB;   // 8 * 512*3328 * 4 = 54.5 MB  (bufB free at head stage)
    float* partO = bufA;   // 8 * 512*128  * 4 = 2 MB     (bufA free at out3 stage)

    // ---- CSR + graph boundaries ----
    hipMemsetAsync(deg, 0, (size_t)NP_PAD * 4, stream);
    hipMemsetAsync(pool512, 0, (size_t)GG * 512 * 4, stream);
    k_deg<<<(EE + 255) / 256, 256, 0, stream>>>(dst, deg, EE);
    k_gptr<<<(NN + 256) / 256, 256, 0, stream>>>(batch, gptr, NN);
    k_scan1<<<NB_SCAN, 256, 0, stream>>>(deg, bsum);
    k_scan2<<<1, 64, 0, stream>>>(bsum, boff, NB_SCAN);
    k_scan3<<<NB_SCAN, 256, 0, stream>>>(deg, boff, ptr, cursor, NN);
    k_place<<<(EE + 255) / 256, 256, 0, stream>>>(src, dst, cursor, csr, EE);

    const int MT = (NN + 127) / 128;  // 782 row tiles

    // ---- conv1 ----
    k_aggr<64><<<(NN + 15) / 16, 256, 0, stream>>>(x, ptr, csr, bufA, NN);
    k_mgemm<64, 64, true, false, true, 0><<<dim3(MT, 1, 1), 256, 0, stream>>>(
        bufA, nullptr, c1w1, c1b1, nullptr, nullptr, bufB, NN, DH);
    k_mgemm<128, 128, true, true, true, 0><<<dim3(MT, 1, 1), 256, 0, stream>>>(
        bufB, nullptr, c1w2, c1b2, bn1g, bn1b, h1, NN, DH);
    k_pool<128><<<dim3(GG, 8), 128, 0, stream>>>(h1, gptr, pool512, 0);

    // ---- conv2 ----
    k_aggr<128><<<(NN + 7) / 8, 256, 0, stream>>>(h1, ptr, csr, bufA, NN);
    k_mgemm<128, 128, true, false, true, 0><<<dim3(MT, 1, 1), 256, 0, stream>>>(
        bufA, nullptr, c2w1, c2b1, nullptr, nullptr, bufB, NN, DH);
    k_mgemm<128, 128, true, true, true, 0><<<dim3(MT, 1, 1), 256, 0, stream>>>(
        bufB, nullptr, c2w2, c2b2, bn2g, bn2b, h2, NN, DH);
    k_pool<128><<<dim3(GG, 8), 128, 0, stream>>>(h2, gptr, pool512, DH);

    // ---- conv3 ----
    k_aggr<128><<<(NN + 7) / 8, 256, 0, stream>>>(h2, ptr, csr, bufA, NN);
    k_mgemm<128, 128, true, false, true, 0><<<dim3(MT, 2, 1), 256, 0, stream>>>(
        bufA, nullptr, c3w1, c3b1, nullptr, nullptr, bufB, NN, DHL);
    k_mgemm<256, 256, true, true, true, 0><<<dim3(MT, 2, 1), 256, 0, stream>>>(
        bufB, nullptr, c3w2, c3b2, bn3g, bn3b, bufA, NN, DHL);
    k_pool<256><<<dim3(GG, 8), 256, 0, stream>>>(bufA, gptr, pool512, 2 * DH);

    // ---- head: partH[z] = (concat(pool512, fp) @ o1w)_chunk_z ; then reduce+BN+ReLU ----
    k_mgemm<RD, 832, false, false, false, 512><<<dim3(4, RH / 128, 8), 256, 0, stream>>>(
        pool512, fp, o1w, nullptr, nullptr, nullptr, partH, GG, RH);
    k_red_head<<<(GG * RH) / 256, 256, 0, stream>>>(partH, o1b, obng, obnb, hmid);

    // ---- out3: out = hmid @ o3w + o3b (split-K partials + reduce) ----
    k_mgemm<RH, 416, false, false, false, 0><<<dim3(4, 1, 8), 256, 0, stream>>>(
        hmid, nullptr, o3w, nullptr, nullptr, nullptr, partO, GG, NC);
    k_red_out<<<(GG * NC) / 256, 256, 0, stream>>>(partO, o3b, out);
}

// Round 3
// 1261.569 us; speedup vs baseline: 1.4219x; 1.0036x over previous
//
#include <hip/hip_runtime.h>
#include <cstdint>
#include <cstddef>

// ---------------- problem constants ----------------
#define NN      100000
#define EE      1600000
#define GG      512
#define F_IN    64
#define DH      128
#define DHL     256
#define NC      128
#define FPD     6144
#define RD      6656        // DH+DH+DHL+FPD
#define RH      3328        // RD/2

static constexpr float BN_SCALE = 0.9999950000374997f; // 1/sqrt(1+1e-5)

#define NB_SCAN 98              // ceil(100000/1024)
#define NP_PAD  (NB_SCAN*1024)  // 100352

typedef __attribute__((ext_vector_type(8))) short bf16x8;
typedef __attribute__((ext_vector_type(4))) float f32x4;
typedef unsigned int uint32;

__device__ __forceinline__ ushort f2bf(float f) {
    uint32 u = __float_as_uint(f);
    uint32 r = u + 0x7fffu + ((u >> 16) & 1u);
    return (ushort)(r >> 16);
}
__device__ __forceinline__ uint32 pk2(float a, float b) {
    return (uint32)f2bf(a) | ((uint32)f2bf(b) << 16);
}
__device__ __forceinline__ void upadd(uint32 p, float& a, float& b) {
    a += __uint_as_float(p << 16);
    b += __uint_as_float(p & 0xffff0000u);
}

// ---------------- CSR build ----------------
__global__ void k_deg(const int* __restrict__ dst, int* __restrict__ deg, int n)
{
    int i = blockIdx.x * 256 + threadIdx.x;
    if (i < n) atomicAdd(&deg[dst[i]], 1);
}

__global__ void k_gptr(const int* __restrict__ batch, int* __restrict__ gptr, int n)
{
    int i = blockIdx.x * 256 + threadIdx.x;
    if (i > n) return;
    if (i == 0) {
        int b0 = batch[0];
        for (int g = 0; g <= b0; ++g) gptr[g] = 0;
    } else if (i == n) {
        int bl = batch[n - 1];
        for (int g = bl + 1; g <= GG; ++g) gptr[g] = n;
    } else {
        int bp = batch[i - 1], bc = batch[i];
        for (int g = bp + 1; g <= bc; ++g) gptr[g] = i;
    }
}

__global__ __launch_bounds__(256) void k_scan1(const int* __restrict__ deg, int* __restrict__ bsum)
{
    __shared__ int sm[256];
    int base = blockIdx.x * 1024 + threadIdx.x * 4;
    int4 v = *(const int4*)(deg + base);
    sm[threadIdx.x] = v.x + v.y + v.z + v.w;
    __syncthreads();
    for (int off = 128; off > 0; off >>= 1) {
        if (threadIdx.x < off) sm[threadIdx.x] += sm[threadIdx.x + off];
        __syncthreads();
    }
    if (threadIdx.x == 0) bsum[blockIdx.x] = sm[0];
}

__global__ void k_scan2(const int* __restrict__ bsum, int* __restrict__ boff, int nb)
{
    if (threadIdx.x == 0) {
        int s = 0;
        for (int i = 0; i < nb; ++i) { boff[i] = s; s += bsum[i]; }
    }
}

__global__ __launch_bounds__(256) void k_scan3(const int* __restrict__ deg, const int* __restrict__ boff,
                                               int* __restrict__ ptr, int* __restrict__ cursor, int n)
{
    __shared__ int sm[256];
    int tid = threadIdx.x;
    int base = blockIdx.x * 1024 + tid * 4;
    int4 v = *(const int4*)(deg + base);
    int t = v.x + v.y + v.z + v.w;
    sm[tid] = t;
    __syncthreads();
    for (int off = 1; off < 256; off <<= 1) {
        int add = (tid >= off) ? sm[tid - off] : 0;
        __syncthreads();
        sm[tid] += add;
        __syncthreads();
    }
    int ex = boff[blockIdx.x] + sm[tid] - t;
    int pr0 = ex, pr1 = ex + v.x, pr2 = pr1 + v.y, pr3 = pr2 + v.z;
    int prs[4] = {pr0, pr1, pr2, pr3};
    for (int j = 0; j < 4; ++j) {
        int idx = base + j;
        if (idx <= n) {
            ptr[idx] = prs[j];
            if (idx < n) cursor[idx] = prs[j];
        }
    }
}

__global__ void k_place(const int* __restrict__ src, const int* __restrict__ dst,
                        int* __restrict__ cursor, int* __restrict__ csr, int n)
{
    int i = blockIdx.x * 256 + threadIdx.x;
    if (i < n) {
        int d = dst[i];
        int p = atomicAdd(&cursor[d], 1);
        csr[p] = src[i];
    }
}

// ---------------- conversions ----------------
__global__ void k_f2bf8(const float* __restrict__ in, ushort* __restrict__ out, int n8)
{
    int i = blockIdx.x * 256 + threadIdx.x;
    if (i >= n8) return;
    float4 a = ((const float4*)in)[i * 2];
    float4 b = ((const float4*)in)[i * 2 + 1];
    uint4 o;
    o.x = pk2(a.x, a.y); o.y = pk2(a.z, a.w);
    o.z = pk2(b.x, b.y); o.w = pk2(b.z, b.w);
    ((uint4*)out)[i] = o;
}

// W[K][N] fp32 -> WT[N][K] bf16  (K,N multiples of 32)
__global__ __launch_bounds__(256) void k_wt(const float* __restrict__ W, ushort* __restrict__ WT,
                                            int K, int N)
{
    __shared__ float tl[32][33];
    int k0 = blockIdx.x * 32, n0 = blockIdx.y * 32;
    int tx = threadIdx.x & 31, ty = threadIdx.x >> 5;
#pragma unroll
    for (int j = 0; j < 4; ++j)
        tl[ty * 4 + j][tx] = W[(size_t)(k0 + ty * 4 + j) * N + n0 + tx];
    __syncthreads();
#pragma unroll
    for (int j = 0; j < 4; ++j)
        WT[(size_t)(n0 + ty * 4 + j) * K + k0 + tx] = f2bf(tl[tx][ty * 4 + j]);
}

// build head A: [512][6656] bf16 = concat(pool512 fp32, fp fp32)
__global__ void k_prep_head(const float* __restrict__ pool, const float* __restrict__ fp,
                            ushort* __restrict__ Ab)
{
    int i = blockIdx.x * 256 + threadIdx.x;       // chunk of 8
    if (i >= GG * RD / 8) return;
    int g = i / (RD / 8);
    int c = (i % (RD / 8)) * 8;
    const float* s = (c < 512) ? pool + (size_t)g * 512 + c
                               : fp + (size_t)g * FPD + (c - 512);
    float4 a = *(const float4*)s;
    float4 b = *(const float4*)(s + 4);
    uint4 o;
    o.x = pk2(a.x, a.y); o.y = pk2(a.z, a.w);
    o.z = pk2(b.x, b.y); o.w = pk2(b.z, b.w);
    ((uint4*)Ab)[i] = o;
}

// ---------------- aggregation (bf16 in/out, fp32 accum) ----------------
template<int D>
__global__ __launch_bounds__(256) void k_aggrb(const ushort* __restrict__ X,
                                               const int* __restrict__ ptr,
                                               const int* __restrict__ csr,
                                               ushort* __restrict__ out, int n_nodes)
{
    constexpr int SL = D / 8;          // lanes per node
    constexpr int NPB = 256 / SL;
    int sl = threadIdx.x % SL, ln = threadIdx.x / SL;
    int n = blockIdx.x * NPB + ln;
    if (n >= n_nodes) return;
    const uint4* Xv = (const uint4*)X;
    float a0 = 0, a1 = 0, a2 = 0, a3 = 0, a4 = 0, a5 = 0, a6 = 0, a7 = 0;
    uint4 v = Xv[(size_t)n * SL + sl];
    upadd(v.x, a0, a1); upadd(v.y, a2, a3); upadd(v.z, a4, a5); upadd(v.w, a6, a7);
    int e0 = ptr[n], e1 = ptr[n + 1];
    for (int e = e0; e < e1; ++e) {
        int s = csr[e];
        v = Xv[(size_t)s * SL + sl];
        upadd(v.x, a0, a1); upadd(v.y, a2, a3); upadd(v.z, a4, a5); upadd(v.w, a6, a7);
    }
    uint4 o;
    o.x = pk2(a0, a1); o.y = pk2(a2, a3); o.z = pk2(a4, a5); o.w = pk2(a6, a7);
    ((uint4*)out)[(size_t)n * SL + sl] = o;
}

// ---------------- bf16 MFMA GEMM ----------------
// C = epi(A[M][K] @ BT[N][K]^T)  all bf16 operands, fp32 accum
// PARTIAL: write raw fp32 partial slab at z*M*NOUT. else bias(+BN)(+ReLU), OUTBF picks bf16/f32 C.
template<bool BNF, bool RELU, bool OUTBF, bool PARTIAL>
__global__ __launch_bounds__(256, 2) void k_bgemm(
    const ushort* __restrict__ A, const ushort* __restrict__ BT,
    const float* __restrict__ bias, const float* __restrict__ bng, const float* __restrict__ bnb,
    void* __restrict__ Cout, int M, int K, int NOUT, int kchunk)
{
    __shared__ ushort As[8][128][8];
    __shared__ ushort Bs[8][128][8];
    const int t = threadIdx.x;
    const int lane = t & 63, w = t >> 6;
    const int wm = w >> 1, wn = w & 1;
    const int fr = lane & 15, fq = lane >> 4;
    const long row0 = (long)blockIdx.x * 128;
    const int col0 = blockIdx.y * 128;
    const int kb = blockIdx.z * kchunk;
    const int kend = kb + kchunk;

    const int s_sub = t >> 3;      // 0..31
    const int s_chk = t & 7;       // 16B chunk (8 k-elems)

    const ushort* aptr[4];
    const ushort* bptr[4];
#pragma unroll
    for (int j = 0; j < 4; ++j) {
        long r = row0 + j * 32 + s_sub;
        long rc = r < (long)M ? r : (long)M - 1;
        aptr[j] = A + rc * K + s_chk * 8;
        bptr[j] = BT + (size_t)(col0 + j * 32 + s_sub) * K + s_chk * 8;
    }

    f32x4 acc[4][4];
#pragma unroll
    for (int m = 0; m < 4; ++m)
#pragma unroll
        for (int n = 0; n < 4; ++n)
            acc[m][n] = (f32x4){0.f, 0.f, 0.f, 0.f};

    uint4 ra[4], rb[4];
#pragma unroll
    for (int j = 0; j < 4; ++j) {
        ra[j] = *(const uint4*)(aptr[j] + kb);
        rb[j] = *(const uint4*)(bptr[j] + kb);
    }

    for (int k0 = kb; k0 < kend; k0 += 64) {
        __syncthreads();
#pragma unroll
        for (int j = 0; j < 4; ++j) {
            *(uint4*)&As[s_chk][j * 32 + s_sub][0] = ra[j];
            *(uint4*)&Bs[s_chk][j * 32 + s_sub][0] = rb[j];
        }
        int kn = (k0 + 64 < kend) ? k0 + 64 : kb;   // tail reload (discarded)
#pragma unroll
        for (int j = 0; j < 4; ++j) {
            ra[j] = *(const uint4*)(aptr[j] + kn);
            rb[j] = *(const uint4*)(bptr[j] + kn);
        }
        __syncthreads();
#pragma unroll
        for (int s = 0; s < 2; ++s) {
            bf16x8 fa[4], fb[4];
#pragma unroll
            for (int m = 0; m < 4; ++m)
                fa[m] = *(const bf16x8*)&As[s * 4 + fq][wm * 64 + m * 16 + fr][0];
#pragma unroll
            for (int n = 0; n < 4; ++n)
                fb[n] = *(const bf16x8*)&Bs[s * 4 + fq][wn * 64 + n * 16 + fr][0];
#pragma unroll
            for (int n = 0; n < 4; ++n)
#pragma unroll
                for (int m = 0; m < 4; ++m)
                    acc[m][n] = __builtin_amdgcn_mfma_f32_16x16x32_bf16(fa[m], fb[n], acc[m][n], 0, 0, 0);
        }
    }

    if constexpr (PARTIAL) {
        float* P = (float*)Cout + (size_t)blockIdx.z * M * NOUT;
#pragma unroll
        for (int n = 0; n < 4; ++n) {
            int col = col0 + wn * 64 + n * 16 + fr;
#pragma unroll
            for (int m = 0; m < 4; ++m) {
                long rbase = row0 + wm * 64 + m * 16 + fq * 4;
#pragma unroll
                for (int r = 0; r < 4; ++r) {
                    long row = rbase + r;
                    if (row < M) P[row * NOUT + col] = acc[m][n][r];
                }
            }
        }
    } else {
#pragma unroll
        for (int n = 0; n < 4; ++n) {
            int col = col0 + wn * 64 + n * 16 + fr;
            float bi = bias[col];
            float g = 1.f, bb = 0.f;
            if constexpr (BNF) { g = bng[col] * BN_SCALE; bb = bnb[col]; }
#pragma unroll
            for (int m = 0; m < 4; ++m) {
                long rbase = row0 + wm * 64 + m * 16 + fq * 4;
#pragma unroll
                for (int r = 0; r < 4; ++r) {
                    long row = rbase + r;
                    if (row < M) {
                        float o = acc[m][n][r] + bi;
                        if constexpr (BNF) o = o * g + bb;
                        if constexpr (RELU) o = fmaxf(o, 0.f);
                        if constexpr (OUTBF) ((ushort*)Cout)[row * NOUT + col] = f2bf(o);
                        else ((float*)Cout)[row * NOUT + col] = o;
                    }
                }
            }
        }
    }
}

// ---------------- split-K reductions ----------------
__global__ void k_red_head(const float* __restrict__ P, const float* __restrict__ bias,
                           const float* __restrict__ g, const float* __restrict__ b,
                           ushort* __restrict__ O)
{
    int i = blockIdx.x * 256 + threadIdx.x;     // 512*3328
    int col = i % RH;
    float s = P[i] + P[(size_t)GG * RH + i];
    float o = (s + bias[col]) * (g[col] * BN_SCALE) + b[col];
    O[i] = f2bf(fmaxf(o, 0.f));
}

__global__ void k_red_out(const float* __restrict__ P, const float* __restrict__ bias,
                          float* __restrict__ O)
{
    int i = blockIdx.x * 256 + threadIdx.x;     // 512*128
    float s = 0.f;
#pragma unroll
    for (int z = 0; z < 13; ++z) s += P[(size_t)z * (GG * NC) + i];
    O[i] = s + bias[i & (NC - 1)];
}

// ---------------- per-graph pooling (bf16 in, block-per-graph, no atomics) ----------------
template<int D>
__global__ __launch_bounds__(256) void k_poolb(const ushort* __restrict__ H,
                                               const int* __restrict__ gptr,
                                               float* __restrict__ pool512, int colOff)
{
    constexpr int SL = D / 8;        // 16 or 32
    constexpr int SUB = 256 / SL;    // 16 or 8
    __shared__ float red[SUB][D];
    int sl = threadIdx.x % SL, su = threadIdx.x / SL;
    int g = blockIdx.x;
    int n0 = gptr[g], n1 = gptr[g + 1];
    float a0 = 0, a1 = 0, a2 = 0, a3 = 0, a4 = 0, a5 = 0, a6 = 0, a7 = 0;
    const uint4* Hv = (const uint4*)H;
    for (int n = n0 + su; n < n1; n += SUB) {
        uint4 v = Hv[(size_t)n * SL + sl];
        upadd(v.x, a0, a1); upadd(v.y, a2, a3); upadd(v.z, a4, a5); upadd(v.w, a6, a7);
    }
    float* rr = &red[su][sl * 8];
    rr[0] = a0; rr[1] = a1; rr[2] = a2; rr[3] = a3;
    rr[4] = a4; rr[5] = a5; rr[6] = a6; rr[7] = a7;
    __syncthreads();
    for (int c = threadIdx.x; c < D; c += 256) {
        float s = 0.f;
#pragma unroll
        for (int u = 0; u < SUB; ++u) s += red[u][c];
        pool512[(size_t)g * 512 + colOff + c] = s;
    }
}

// ---------------- launch ----------------
extern "C" void kernel_launch(void* const* d_in, const int* in_sizes, int n_in,
                              void* d_out, int out_size, void* d_ws, size_t ws_size,
                              hipStream_t stream)
{
    const float* x     = (const float*)d_in[0];
    const int*   ei    = (const int*)d_in[1];
    const int*   src   = ei;
    const int*   dst   = ei + EE;
    const int*   batch = (const int*)d_in[2];
    const float* fp    = (const float*)d_in[3];
    const float* c1w1  = (const float*)d_in[4];
    const float* c1b1  = (const float*)d_in[5];
    const float* c1w2  = (const float*)d_in[6];
    const float* c1b2  = (const float*)d_in[7];
    const float* c2w1  = (const float*)d_in[8];
    const float* c2b1  = (const float*)d_in[9];
    const float* c2w2  = (const float*)d_in[10];
    const float* c2b2  = (const float*)d_in[11];
    const float* c3w1  = (const float*)d_in[12];
    const float* c3b1  = (const float*)d_in[13];
    const float* c3w2  = (const float*)d_in[14];
    const float* c3b2  = (const float*)d_in[15];
    const float* bn1g  = (const float*)d_in[16];
    const float* bn1b  = (const float*)d_in[17];
    const float* bn2g  = (const float*)d_in[18];
    const float* bn2b  = (const float*)d_in[19];
    const float* bn3g  = (const float*)d_in[20];
    const float* bn3b  = (const float*)d_in[21];
    const float* o1w   = (const float*)d_in[22];
    const float* o1b   = (const float*)d_in[23];
    const float* obng  = (const float*)d_in[24];
    const float* obnb  = (const float*)d_in[25];
    const float* o3w   = (const float*)d_in[26];
    const float* o3b   = (const float*)d_in[27];
    float* out = (float*)d_out;

    char* ws = (char*)d_ws;
    size_t off = 0;
    auto alloc = [&](size_t bytes) {
        size_t r = off;
        off = (off + bytes + 255) & ~(size_t)255;
        return (void*)(ws + r);
    };
    ushort* aggbuf = (ushort*)alloc((size_t)NN * 256 * 2);
    ushort* midbuf = (ushort*)alloc((size_t)NN * 256 * 2);
    ushort* xbf    = (ushort*)alloc((size_t)NN * 64 * 2);
    ushort* h1     = (ushort*)alloc((size_t)NN * 128 * 2);
    ushort* h2     = (ushort*)alloc((size_t)NN * 128 * 2);
    ushort* headA  = (ushort*)alloc((size_t)GG * RD * 2);
    ushort* hmid   = (ushort*)alloc((size_t)GG * RH * 2);
    ushort* wtc1a  = (ushort*)alloc((size_t)128 * 64 * 2);
    ushort* wtc1b  = (ushort*)alloc((size_t)128 * 128 * 2);
    ushort* wtc2a  = (ushort*)alloc((size_t)128 * 128 * 2);
    ushort* wtc2b  = (ushort*)alloc((size_t)128 * 128 * 2);
    ushort* wtc3a  = (ushort*)alloc((size_t)256 * 128 * 2);
    ushort* wtc3b  = (ushort*)alloc((size_t)256 * 256 * 2);
    ushort* wtH    = (ushort*)alloc((size_t)RH * RD * 2);
    ushort* wtO    = (ushort*)alloc((size_t)NC * RH * 2);
    float* pool512 = (float*)alloc((size_t)GG * 512 * 4);
    float* partH   = (float*)alloc((size_t)2 * GG * RH * 4);
    float* partO   = (float*)alloc((size_t)13 * GG * NC * 4);
    int* deg    = (int*)alloc((size_t)NP_PAD * 4);
    int* ptr    = (int*)alloc((size_t)(NN + 1) * 4);
    int* cursor = (int*)alloc((size_t)NN * 4);
    int* bsum   = (int*)alloc((size_t)NB_SCAN * 4);
    int* boff   = (int*)alloc((size_t)NB_SCAN * 4);
    int* gptr   = (int*)alloc((size_t)(GG + 1) * 4);
    int* csr    = (int*)alloc((size_t)EE * 4);
    (void)ws_size; (void)in_sizes; (void)n_in; (void)out_size;

    // ---- CSR + graph boundaries ----
    hipMemsetAsync(deg, 0, (size_t)NP_PAD * 4, stream);
    k_deg<<<(EE + 255) / 256, 256, 0, stream>>>(dst, deg, EE);
    k_gptr<<<(NN + 256) / 256, 256, 0, stream>>>(batch, gptr, NN);
    k_scan1<<<NB_SCAN, 256, 0, stream>>>(deg, bsum);
    k_scan2<<<1, 64, 0, stream>>>(bsum, boff, NB_SCAN);
    k_scan3<<<NB_SCAN, 256, 0, stream>>>(deg, boff, ptr, cursor, NN);
    k_place<<<(EE + 255) / 256, 256, 0, stream>>>(src, dst, cursor, csr, EE);

    // ---- one-time conversions ----
    k_f2bf8<<<(NN * 64 / 8 + 255) / 256, 256, 0, stream>>>(x, xbf, NN * 64 / 8);
    k_wt<<<dim3(64 / 32, 128 / 32), 256, 0, stream>>>(c1w1, wtc1a, 64, 128);
    k_wt<<<dim3(128 / 32, 128 / 32), 256, 0, stream>>>(c1w2, wtc1b, 128, 128);
    k_wt<<<dim3(128 / 32, 128 / 32), 256, 0, stream>>>(c2w1, wtc2a, 128, 128);
    k_wt<<<dim3(128 / 32, 128 / 32), 256, 0, stream>>>(c2w2, wtc2b, 128, 128);
    k_wt<<<dim3(128 / 32, 256 / 32), 256, 0, stream>>>(c3w1, wtc3a, 128, 256);
    k_wt<<<dim3(256 / 32, 256 / 32), 256, 0, stream>>>(c3w2, wtc3b, 256, 256);
    k_wt<<<dim3(RD / 32, RH / 32), 256, 0, stream>>>(o1w, wtH, RD, RH);
    k_wt<<<dim3(RH / 32, NC / 32), 256, 0, stream>>>(o3w, wtO, RH, NC);

    const int MT = (NN + 127) / 128;  // 782

    // ---- conv1 ----
    k_aggrb<64><<<(NN + 31) / 32, 256, 0, stream>>>(xbf, ptr, csr, aggbuf, NN);
    k_bgemm<false, true, true, false><<<dim3(MT, 1, 1), 256, 0, stream>>>(
        aggbuf, wtc1a, c1b1, nullptr, nullptr, midbuf, NN, 64, 128, 64);
    k_bgemm<true, true, true, false><<<dim3(MT, 1, 1), 256, 0, stream>>>(
        midbuf, wtc1b, c1b2, bn1g, bn1b, h1, NN, 128, 128, 128);
    k_poolb<128><<<GG, 256, 0, stream>>>(h1, gptr, pool512, 0);

    // ---- conv2 ----
    k_aggrb<128><<<(NN + 15) / 16, 256, 0, stream>>>(h1, ptr, csr, aggbuf, NN);
    k_bgemm<false, true, true, false><<<dim3(MT, 1, 1), 256, 0, stream>>>(
        aggbuf, wtc2a, c2b1, nullptr, nullptr, midbuf, NN, 128, 128, 128);
    k_bgemm<true, true, true, false><<<dim3(MT, 1, 1), 256, 0, stream>>>(
        midbuf, wtc2b, c2b2, bn2g, bn2b, h2, NN, 128, 128, 128);
    k_poolb<128><<<GG, 256, 0, stream>>>(h2, gptr, pool512, DH);

    // ---- conv3 ----  (h3 -> aggbuf after conv3a frees it)
    k_aggrb<128><<<(NN + 15) / 16, 256, 0, stream>>>(h2, ptr, csr, aggbuf, NN);
    k_bgemm<false, true, true, false><<<dim3(MT, 2, 1), 256, 0, stream>>>(
        aggbuf, wtc3a, c3b1, nullptr, nullptr, midbuf, NN, 128, 256, 128);
    k_bgemm<true, true, true, false><<<dim3(MT, 2, 1), 256, 0, stream>>>(
        midbuf, wtc3b, c3b2, bn3g, bn3b, aggbuf, NN, 256, 256, 256);
    k_poolb<256><<<GG, 256, 0, stream>>>(aggbuf, gptr, pool512, 2 * DH);

    // ---- head ----
    k_prep_head<<<(GG * RD / 8 + 255) / 256, 256, 0, stream>>>(pool512, fp, headA);
    k_bgemm<false, false, false, true><<<dim3(4, RH / 128, 2), 256, 0, stream>>>(
        headA, wtH, nullptr, nullptr, nullptr, partH, GG, RD, RH, RD / 2);
    k_red_head<<<(GG * RH) / 256, 256, 0, stream>>>(partH, o1b, obng, obnb, hmid);

    // ---- out3 ----
    k_bgemm<false, false, false, true><<<dim3(4, 1, 13), 256, 0, stream>>>(
        hmid, wtO, nullptr, nullptr, nullptr, partO, GG, RH, NC, RH / 13);
    k_red_out<<<(GG * NC) / 256, 256, 0, stream>>>(partO, o3b, out);
}

// Round 4
// 1052.038 us; speedup vs baseline: 1.7051x; 1.1992x over previous
//
#include <hip/hip_runtime.h>
#include <cstdint>
#include <cstddef>

// ---------------- problem constants ----------------
#define NN      100000
#define EE      1600000
#define GG      512
#define F_IN    64
#define DH      128
#define DHL     256
#define NC      128
#define FPD     6144
#define RD      6656        // DH+DH+DHL+FPD
#define RH      3328        // RD/2

static constexpr float BN_SCALE = 0.9999950000374997f; // 1/sqrt(1+1e-5)

#define NB_SCAN 98              // ceil(100000/1024)
#define NP_PAD  (NB_SCAN*1024)  // 100352

#define HZ      8               // head split-K slabs
#define OZ      26              // out3 split-K slabs

typedef __attribute__((ext_vector_type(8))) short bf16x8;
typedef __attribute__((ext_vector_type(4))) float f32x4;
typedef unsigned int uint32;

__device__ __forceinline__ ushort f2bf(float f) {
    uint32 u = __float_as_uint(f);
    uint32 r = u + 0x7fffu + ((u >> 16) & 1u);
    return (ushort)(r >> 16);
}
__device__ __forceinline__ float bf2f(ushort h) {
    return __uint_as_float(((uint32)h) << 16);
}
__device__ __forceinline__ uint32 pk2(float a, float b) {
    return (uint32)f2bf(a) | ((uint32)f2bf(b) << 16);
}
__device__ __forceinline__ void upadd(uint32 p, float& a, float& b) {
    a += __uint_as_float(p << 16);
    b += __uint_as_float(p & 0xffff0000u);
}

// ---------------- CSR build ----------------
__global__ void k_deg(const int* __restrict__ dst, int* __restrict__ deg, int n)
{
    int i = blockIdx.x * 256 + threadIdx.x;
    if (i < n) atomicAdd(&deg[dst[i]], 1);
}

__global__ void k_gptr(const int* __restrict__ batch, int* __restrict__ gptr, int n)
{
    int i = blockIdx.x * 256 + threadIdx.x;
    if (i > n) return;
    if (i == 0) {
        int b0 = batch[0];
        for (int g = 0; g <= b0; ++g) gptr[g] = 0;
    } else if (i == n) {
        int bl = batch[n - 1];
        for (int g = bl + 1; g <= GG; ++g) gptr[g] = n;
    } else {
        int bp = batch[i - 1], bc = batch[i];
        for (int g = bp + 1; g <= bc; ++g) gptr[g] = i;
    }
}

__global__ __launch_bounds__(256) void k_scan1(const int* __restrict__ deg, int* __restrict__ bsum)
{
    __shared__ int sm[256];
    int base = blockIdx.x * 1024 + threadIdx.x * 4;
    int4 v = *(const int4*)(deg + base);
    sm[threadIdx.x] = v.x + v.y + v.z + v.w;
    __syncthreads();
    for (int off = 128; off > 0; off >>= 1) {
        if (threadIdx.x < off) sm[threadIdx.x] += sm[threadIdx.x + off];
        __syncthreads();
    }
    if (threadIdx.x == 0) bsum[blockIdx.x] = sm[0];
}

__global__ void k_scan2(const int* __restrict__ bsum, int* __restrict__ boff, int nb)
{
    if (threadIdx.x == 0) {
        int s = 0;
        for (int i = 0; i < nb; ++i) { boff[i] = s; s += bsum[i]; }
    }
}

__global__ __launch_bounds__(256) void k_scan3(const int* __restrict__ deg, const int* __restrict__ boff,
                                               int* __restrict__ ptr, int* __restrict__ cursor, int n)
{
    __shared__ int sm[256];
    int tid = threadIdx.x;
    int base = blockIdx.x * 1024 + tid * 4;
    int4 v = *(const int4*)(deg + base);
    int t = v.x + v.y + v.z + v.w;
    sm[tid] = t;
    __syncthreads();
    for (int off = 1; off < 256; off <<= 1) {
        int add = (tid >= off) ? sm[tid - off] : 0;
        __syncthreads();
        sm[tid] += add;
        __syncthreads();
    }
    int ex = boff[blockIdx.x] + sm[tid] - t;
    int pr0 = ex, pr1 = ex + v.x, pr2 = pr1 + v.y, pr3 = pr2 + v.z;
    int prs[4] = {pr0, pr1, pr2, pr3};
    for (int j = 0; j < 4; ++j) {
        int idx = base + j;
        if (idx <= n) {
            ptr[idx] = prs[j];
            if (idx < n) cursor[idx] = prs[j];
        }
    }
}

__global__ void k_place(const int* __restrict__ src, const int* __restrict__ dst,
                        int* __restrict__ cursor, int* __restrict__ csr, int n)
{
    int i = blockIdx.x * 256 + threadIdx.x;
    if (i < n) {
        int d = dst[i];
        int p = atomicAdd(&cursor[d], 1);
        csr[p] = src[i];
    }
}

// ---------------- conversions ----------------
__global__ void k_f2bf8(const float* __restrict__ in, ushort* __restrict__ out, int n8)
{
    int i = blockIdx.x * 256 + threadIdx.x;
    if (i >= n8) return;
    float4 a = ((const float4*)in)[i * 2];
    float4 b = ((const float4*)in)[i * 2 + 1];
    uint4 o;
    o.x = pk2(a.x, a.y); o.y = pk2(a.z, a.w);
    o.z = pk2(b.x, b.y); o.w = pk2(b.z, b.w);
    ((uint4*)out)[i] = o;
}

// W[K][N] fp32 -> WT[N][K] bf16  (K,N multiples of 32)
__global__ __launch_bounds__(256) void k_wt(const float* __restrict__ W, ushort* __restrict__ WT,
                                            int K, int N)
{
    __shared__ float tl[32][33];
    int k0 = blockIdx.x * 32, n0 = blockIdx.y * 32;
    int tx = threadIdx.x & 31, ty = threadIdx.x >> 5;
#pragma unroll
    for (int j = 0; j < 4; ++j)
        tl[ty * 4 + j][tx] = W[(size_t)(k0 + ty * 4 + j) * N + n0 + tx];
    __syncthreads();
#pragma unroll
    for (int j = 0; j < 4; ++j)
        WT[(size_t)(n0 + ty * 4 + j) * K + k0 + tx] = f2bf(tl[tx][ty * 4 + j]);
}

// build head A: [512][6656] bf16 = concat(pool512 fp32, fp fp32)
__global__ void k_prep_head(const float* __restrict__ pool, const float* __restrict__ fp,
                            ushort* __restrict__ Ab)
{
    int i = blockIdx.x * 256 + threadIdx.x;       // chunk of 8
    if (i >= GG * RD / 8) return;
    int g = i / (RD / 8);
    int c = (i % (RD / 8)) * 8;
    const float* s = (c < 512) ? pool + (size_t)g * 512 + c
                               : fp + (size_t)g * FPD + (c - 512);
    float4 a = *(const float4*)s;
    float4 b = *(const float4*)(s + 4);
    uint4 o;
    o.x = pk2(a.x, a.y); o.y = pk2(a.z, a.w);
    o.z = pk2(b.x, b.y); o.w = pk2(b.z, b.w);
    ((uint4*)Ab)[i] = o;
}

// ---------------- aggregation (bf16 in/out, fp32 accum) ----------------
template<int D>
__global__ __launch_bounds__(256) void k_aggrb(const ushort* __restrict__ X,
                                               const int* __restrict__ ptr,
                                               const int* __restrict__ csr,
                                               ushort* __restrict__ out, int n_nodes)
{
    constexpr int SL = D / 8;          // lanes per node
    constexpr int NPB = 256 / SL;
    int sl = threadIdx.x % SL, ln = threadIdx.x / SL;
    int n = blockIdx.x * NPB + ln;
    if (n >= n_nodes) return;
    const uint4* Xv = (const uint4*)X;
    float a0 = 0, a1 = 0, a2 = 0, a3 = 0, a4 = 0, a5 = 0, a6 = 0, a7 = 0;
    uint4 v = Xv[(size_t)n * SL + sl];
    upadd(v.x, a0, a1); upadd(v.y, a2, a3); upadd(v.z, a4, a5); upadd(v.w, a6, a7);
    int e0 = ptr[n], e1 = ptr[n + 1];
    for (int e = e0; e < e1; ++e) {
        int s = csr[e];
        v = Xv[(size_t)s * SL + sl];
        upadd(v.x, a0, a1); upadd(v.y, a2, a3); upadd(v.z, a4, a5); upadd(v.w, a6, a7);
    }
    uint4 o;
    o.x = pk2(a0, a1); o.y = pk2(a2, a3); o.z = pk2(a4, a5); o.w = pk2(a6, a7);
    ((uint4*)out)[(size_t)n * SL + sl] = o;
}

// ---------------- direct-to-register MFMA GEMM (no LDS, no barriers) ----------------
// C = epi(A[M][K] @ BT[N][K]^T), bf16 operands, fp32 accum.
// GRID: 0 = generic (bx = id%nbx, by = id/nbx, bz=0)
//       1 = head   (4 x 26 x HZ), XCD-chunked so z-slice z lives on XCD z
//       2 = out3   (4 x 1 x OZ)
// EPI:  0 = bias+relu -> bf16 ; 1 = bias+bn+relu -> bf16 ;
//       2 = raw f32 partial slab[bz] ; 3 = raw bf16 partial slab[bz]
template<int GRID, int EPI>
__global__ __launch_bounds__(256) void k_rgemm(
    const ushort* __restrict__ A, const ushort* __restrict__ BT,
    const float* __restrict__ bias, const float* __restrict__ bng, const float* __restrict__ bnb,
    void* __restrict__ Cout, int M, int K, int NOUT, int nbx, int kchunk)
{
    int id = blockIdx.x;
    int bx, by, bz;
    if constexpr (GRID == 1) {
        int vid = (id & 7) * (4 * 26 * HZ / 8) + (id >> 3);  // chunk 104 per XCD
        bx = vid & 3; int cz = vid >> 2; by = cz % 26; bz = cz / 26;
    } else if constexpr (GRID == 2) {
        bx = id & 3; by = 0; bz = id >> 2;
    } else {
        bx = id % nbx; by = id / nbx; bz = 0;
    }
    const int t = threadIdx.x;
    const int lane = t & 63, w = t >> 6;
    const int wm = w >> 1, wn = w & 1;
    const int fr = lane & 15, fq = lane >> 4;
    const long row0 = (long)bx * 128 + wm * 64;      // wave's row base
    const int col0 = by * 128 + wn * 64;             // wave's col base
    const int kb = bz * kchunk;
    const int nks = kchunk >> 5;                     // 32-k sets (always even here)

    const ushort* ap[4];
    const ushort* bp[4];
#pragma unroll
    for (int m = 0; m < 4; ++m) {
        long r = row0 + m * 16 + fr;
        if (r >= M) r = M - 1;                       // clamp (stores guarded)
        ap[m] = A + r * (long)K + kb + fq * 8;
    }
#pragma unroll
    for (int n = 0; n < 4; ++n)
        bp[n] = BT + (size_t)(col0 + n * 16 + fr) * K + kb + fq * 8;

    f32x4 acc[4][4];
#pragma unroll
    for (int m = 0; m < 4; ++m)
#pragma unroll
        for (int n = 0; n < 4; ++n)
            acc[m][n] = (f32x4){0.f, 0.f, 0.f, 0.f};

    bf16x8 aS0[4], bS0[4], aS1[4], bS1[4];

#define LOADSET(sA, sB, KS)                                            \
    {                                                                  \
        int _o = (KS) * 32;                                            \
        _Pragma("unroll")                                              \
        for (int j = 0; j < 4; ++j) sA[j] = *(const bf16x8*)(ap[j] + _o); \
        _Pragma("unroll")                                              \
        for (int j = 0; j < 4; ++j) sB[j] = *(const bf16x8*)(bp[j] + _o); \
    }
#define MFMASET(sA, sB)                                                \
    _Pragma("unroll")                                                  \
    for (int n = 0; n < 4; ++n)                                        \
        _Pragma("unroll")                                              \
        for (int m = 0; m < 4; ++m)                                    \
            acc[m][n] = __builtin_amdgcn_mfma_f32_16x16x32_bf16(sA[m], sB[n], acc[m][n], 0, 0, 0);

    LOADSET(aS0, bS0, 0)
    for (int ks = 0; ks < nks; ks += 2) {
        LOADSET(aS1, bS1, ks + 1)
        MFMASET(aS0, bS0)
        if (ks + 2 < nks) LOADSET(aS0, bS0, ks + 2)
        MFMASET(aS1, bS1)
    }
#undef LOADSET
#undef MFMASET

    if constexpr (EPI == 2 || EPI == 3) {
#pragma unroll
        for (int n = 0; n < 4; ++n) {
            int col = col0 + n * 16 + fr;
#pragma unroll
            for (int m = 0; m < 4; ++m) {
                long rbase = row0 + m * 16 + fq * 4;
#pragma unroll
                for (int r = 0; r < 4; ++r) {
                    long row = rbase + r;
                    if (row < M) {
                        if constexpr (EPI == 2)
                            ((float*)Cout)[(size_t)bz * M * NOUT + row * NOUT + col] = acc[m][n][r];
                        else
                            ((ushort*)Cout)[(size_t)bz * M * NOUT + row * NOUT + col] = f2bf(acc[m][n][r]);
                    }
                }
            }
        }
    } else {
#pragma unroll
        for (int n = 0; n < 4; ++n) {
            int col = col0 + n * 16 + fr;
            float bi = bias[col];
            float g = 1.f, bb = 0.f;
            if constexpr (EPI == 1) { g = bng[col] * BN_SCALE; bb = bnb[col]; }
#pragma unroll
            for (int m = 0; m < 4; ++m) {
                long rbase = row0 + m * 16 + fq * 4;
#pragma unroll
                for (int r = 0; r < 4; ++r) {
                    long row = rbase + r;
                    if (row < M) {
                        float o = acc[m][n][r] + bi;
                        if constexpr (EPI == 1) o = o * g + bb;
                        o = fmaxf(o, 0.f);
                        ((ushort*)Cout)[row * NOUT + col] = f2bf(o);
                    }
                }
            }
        }
    }
}

// ---------------- split-K reductions ----------------
__global__ void k_red_head(const ushort* __restrict__ P, const float* __restrict__ bias,
                           const float* __restrict__ g, const float* __restrict__ b,
                           ushort* __restrict__ O)
{
    int i = blockIdx.x * 256 + threadIdx.x;     // 512*3328
    int col = i % RH;
    float s = 0.f;
#pragma unroll
    for (int z = 0; z < HZ; ++z) s += bf2f(P[(size_t)z * (GG * RH) + i]);
    float o = (s + bias[col]) * (g[col] * BN_SCALE) + b[col];
    O[i] = f2bf(fmaxf(o, 0.f));
}

__global__ void k_red_out(const float* __restrict__ P, const float* __restrict__ bias,
                          float* __restrict__ O)
{
    int i = blockIdx.x * 256 + threadIdx.x;     // 512*128
    float s = 0.f;
#pragma unroll
    for (int z = 0; z < OZ; ++z) s += P[(size_t)z * (GG * NC) + i];
    O[i] = s + bias[i & (NC - 1)];
}

// ---------------- per-graph pooling (bf16 in, block-per-graph, no atomics) ----------------
template<int D>
__global__ __launch_bounds__(256) void k_poolb(const ushort* __restrict__ H,
                                               const int* __restrict__ gptr,
                                               float* __restrict__ pool512, int colOff)
{
    constexpr int SL = D / 8;        // 16 or 32
    constexpr int SUB = 256 / SL;    // 16 or 8
    __shared__ float red[SUB][D];
    int sl = threadIdx.x % SL, su = threadIdx.x / SL;
    int g = blockIdx.x;
    int n0 = gptr[g], n1 = gptr[g + 1];
    float a0 = 0, a1 = 0, a2 = 0, a3 = 0, a4 = 0, a5 = 0, a6 = 0, a7 = 0;
    const uint4* Hv = (const uint4*)H;
    for (int n = n0 + su; n < n1; n += SUB) {
        uint4 v = Hv[(size_t)n * SL + sl];
        upadd(v.x, a0, a1); upadd(v.y, a2, a3); upadd(v.z, a4, a5); upadd(v.w, a6, a7);
    }
    float* rr = &red[su][sl * 8];
    rr[0] = a0; rr[1] = a1; rr[2] = a2; rr[3] = a3;
    rr[4] = a4; rr[5] = a5; rr[6] = a6; rr[7] = a7;
    __syncthreads();
    for (int c = threadIdx.x; c < D; c += 256) {
        float s = 0.f;
#pragma unroll
        for (int u = 0; u < SUB; ++u) s += red[u][c];
        pool512[(size_t)g * 512 + colOff + c] = s;
    }
}

// ---------------- launch ----------------
extern "C" void kernel_launch(void* const* d_in, const int* in_sizes, int n_in,
                              void* d_out, int out_size, void* d_ws, size_t ws_size,
                              hipStream_t stream)
{
    const float* x     = (const float*)d_in[0];
    const int*   ei    = (const int*)d_in[1];
    const int*   src   = ei;
    const int*   dst   = ei + EE;
    const int*   batch = (const int*)d_in[2];
    const float* fp    = (const float*)d_in[3];
    const float* c1w1  = (const float*)d_in[4];
    const float* c1b1  = (const float*)d_in[5];
    const float* c1w2  = (const float*)d_in[6];
    const float* c1b2  = (const float*)d_in[7];
    const float* c2w1  = (const float*)d_in[8];
    const float* c2b1  = (const float*)d_in[9];
    const float* c2w2  = (const float*)d_in[10];
    const float* c2b2  = (const float*)d_in[11];
    const float* c3w1  = (const float*)d_in[12];
    const float* c3b1  = (const float*)d_in[13];
    const float* c3w2  = (const float*)d_in[14];
    const float* c3b2  = (const float*)d_in[15];
    const float* bn1g  = (const float*)d_in[16];
    const float* bn1b  = (const float*)d_in[17];
    const float* bn2g  = (const float*)d_in[18];
    const float* bn2b  = (const float*)d_in[19];
    const float* bn3g  = (const float*)d_in[20];
    const float* bn3b  = (const float*)d_in[21];
    const float* o1w   = (const float*)d_in[22];
    const float* o1b   = (const float*)d_in[23];
    const float* obng  = (const float*)d_in[24];
    const float* obnb  = (const float*)d_in[25];
    const float* o3w   = (const float*)d_in[26];
    const float* o3b   = (const float*)d_in[27];
    float* out = (float*)d_out;

    char* ws = (char*)d_ws;
    size_t off = 0;
    auto alloc = [&](size_t bytes) {
        size_t r = off;
        off = (off + bytes + 255) & ~(size_t)255;
        return (void*)(ws + r);
    };
    ushort* aggbuf = (ushort*)alloc((size_t)NN * 256 * 2);
    ushort* midbuf = (ushort*)alloc((size_t)NN * 256 * 2);
    ushort* xbf    = (ushort*)alloc((size_t)NN * 64 * 2);
    ushort* h1     = (ushort*)alloc((size_t)NN * 128 * 2);
    ushort* h2     = (ushort*)alloc((size_t)NN * 128 * 2);
    ushort* headA  = (ushort*)alloc((size_t)GG * RD * 2);
    ushort* hmid   = (ushort*)alloc((size_t)GG * RH * 2);
    ushort* wtc1a  = (ushort*)alloc((size_t)128 * 64 * 2);
    ushort* wtc1b  = (ushort*)alloc((size_t)128 * 128 * 2);
    ushort* wtc2a  = (ushort*)alloc((size_t)128 * 128 * 2);
    ushort* wtc2b  = (ushort*)alloc((size_t)128 * 128 * 2);
    ushort* wtc3a  = (ushort*)alloc((size_t)256 * 128 * 2);
    ushort* wtc3b  = (ushort*)alloc((size_t)256 * 256 * 2);
    ushort* wtH    = (ushort*)alloc((size_t)RH * RD * 2);
    ushort* wtO    = (ushort*)alloc((size_t)NC * RH * 2);
    float* pool512 = (float*)alloc((size_t)GG * 512 * 4);
    ushort* partH  = (ushort*)alloc((size_t)HZ * GG * RH * 2);
    float*  partO  = (float*)alloc((size_t)OZ * GG * NC * 4);
    int* deg    = (int*)alloc((size_t)NP_PAD * 4);
    int* ptr    = (int*)alloc((size_t)(NN + 1) * 4);
    int* cursor = (int*)alloc((size_t)NN * 4);
    int* bsum   = (int*)alloc((size_t)NB_SCAN * 4);
    int* boff   = (int*)alloc((size_t)NB_SCAN * 4);
    int* gptr   = (int*)alloc((size_t)(GG + 1) * 4);
    int* csr    = (int*)alloc((size_t)EE * 4);
    (void)ws_size; (void)in_sizes; (void)n_in; (void)out_size;

    // ---- CSR + graph boundaries ----
    hipMemsetAsync(deg, 0, (size_t)NP_PAD * 4, stream);
    k_deg<<<(EE + 255) / 256, 256, 0, stream>>>(dst, deg, EE);
    k_gptr<<<(NN + 256) / 256, 256, 0, stream>>>(batch, gptr, NN);
    k_scan1<<<NB_SCAN, 256, 0, stream>>>(deg, bsum);
    k_scan2<<<1, 64, 0, stream>>>(bsum, boff, NB_SCAN);
    k_scan3<<<NB_SCAN, 256, 0, stream>>>(deg, boff, ptr, cursor, NN);
    k_place<<<(EE + 255) / 256, 256, 0, stream>>>(src, dst, cursor, csr, EE);

    // ---- one-time conversions ----
    k_f2bf8<<<(NN * 64 / 8 + 255) / 256, 256, 0, stream>>>(x, xbf, NN * 64 / 8);
    k_wt<<<dim3(64 / 32, 128 / 32), 256, 0, stream>>>(c1w1, wtc1a, 64, 128);
    k_wt<<<dim3(128 / 32, 128 / 32), 256, 0, stream>>>(c1w2, wtc1b, 128, 128);
    k_wt<<<dim3(128 / 32, 128 / 32), 256, 0, stream>>>(c2w1, wtc2a, 128, 128);
    k_wt<<<dim3(128 / 32, 128 / 32), 256, 0, stream>>>(c2w2, wtc2b, 128, 128);
    k_wt<<<dim3(128 / 32, 256 / 32), 256, 0, stream>>>(c3w1, wtc3a, 128, 256);
    k_wt<<<dim3(256 / 32, 256 / 32), 256, 0, stream>>>(c3w2, wtc3b, 256, 256);
    k_wt<<<dim3(RD / 32, RH / 32), 256, 0, stream>>>(o1w, wtH, RD, RH);
    k_wt<<<dim3(RH / 32, NC / 32), 256, 0, stream>>>(o3w, wtO, RH, NC);

    const int MT = (NN + 127) / 128;  // 782 row tiles

    // ---- conv1 ----
    k_aggrb<64><<<(NN + 31) / 32, 256, 0, stream>>>(xbf, ptr, csr, aggbuf, NN);
    k_rgemm<0, 0><<<MT, 256, 0, stream>>>(aggbuf, wtc1a, c1b1, nullptr, nullptr,
                                          midbuf, NN, 64, 128, MT, 64);
    k_rgemm<0, 1><<<MT, 256, 0, stream>>>(midbuf, wtc1b, c1b2, bn1g, bn1b,
                                          h1, NN, 128, 128, MT, 128);
    k_poolb<128><<<GG, 256, 0, stream>>>(h1, gptr, pool512, 0);

    // ---- conv2 ----
    k_aggrb<128><<<(NN + 15) / 16, 256, 0, stream>>>(h1, ptr, csr, aggbuf, NN);
    k_rgemm<0, 0><<<MT, 256, 0, stream>>>(aggbuf, wtc2a, c2b1, nullptr, nullptr,
                                          midbuf, NN, 128, 128, MT, 128);
    k_rgemm<0, 1><<<MT, 256, 0, stream>>>(midbuf, wtc2b, c2b2, bn2g, bn2b,
                                          h2, NN, 128, 128, MT, 128);
    k_poolb<128><<<GG, 256, 0, stream>>>(h2, gptr, pool512, DH);

    // ---- conv3 ---- (h3 -> aggbuf after conv3a consumes it)
    k_aggrb<128><<<(NN + 15) / 16, 256, 0, stream>>>(h2, ptr, csr, aggbuf, NN);
    k_rgemm<0, 0><<<MT * 2, 256, 0, stream>>>(aggbuf, wtc3a, c3b1, nullptr, nullptr,
                                              midbuf, NN, 128, 256, MT, 128);
    k_rgemm<0, 1><<<MT * 2, 256, 0, stream>>>(midbuf, wtc3b, c3b2, bn3g, bn3b,
                                              aggbuf, NN, 256, 256, MT, 256);
    k_poolb<256><<<GG, 256, 0, stream>>>(aggbuf, gptr, pool512, 2 * DH);

    // ---- head: split-K=8, XCD-chunked (z-slice <-> XCD), bf16 partials ----
    k_prep_head<<<(GG * RD / 8 + 255) / 256, 256, 0, stream>>>(pool512, fp, headA);
    k_rgemm<1, 3><<<4 * 26 * HZ, 256, 0, stream>>>(headA, wtH, nullptr, nullptr, nullptr,
                                                   partH, GG, RD, RH, 0, RD / HZ);
    k_red_head<<<(GG * RH) / 256, 256, 0, stream>>>(partH, o1b, obng, obnb, hmid);

    // ---- out3: split-K=26, f32 partials ----
    k_rgemm<2, 2><<<4 * OZ, 256, 0, stream>>>(hmid, wtO, nullptr, nullptr, nullptr,
                                              partO, GG, RH, NC, 0, RH / OZ);
    k_red_out<<<(GG * NC) / 256, 256, 0, stream>>>(partO, o3b, out);
}

// Round 5
// 839.419 us; speedup vs baseline: 2.1370x; 1.2533x over previous
//
#include <hip/hip_runtime.h>
#include <cstdint>
#include <cstddef>

// ---------------- problem constants ----------------
#define NN      100000
#define EE      1600000
#define GG      512
#define F_IN    64
#define DH      128
#define DHL     256
#define NC      128
#define FPD     6144
#define RD      6656        // DH+DH+DHL+FPD
#define RH      3328        // RD/2

static constexpr float BN_SCALE = 0.9999950000374997f; // 1/sqrt(1+1e-5)

#define NB_SCAN 98              // ceil(100000/1024)
#define NP_PAD  (NB_SCAN*1024)  // 100352

#define HZ      8               // head split-K slabs
#define OZ      26              // out3 split-K slabs

#define NBK     391             // edge buckets of 256 nodes: ceil(100000/256)
#define EPB     8192            // edges per kp_a block

typedef __attribute__((ext_vector_type(8))) short bf16x8;
typedef __attribute__((ext_vector_type(4))) float f32x4;
typedef unsigned int uint32;

__device__ __forceinline__ ushort f2bf(float f) {
    uint32 u = __float_as_uint(f);
    uint32 r = u + 0x7fffu + ((u >> 16) & 1u);
    return (ushort)(r >> 16);
}
__device__ __forceinline__ float bf2f(ushort h) {
    return __uint_as_float(((uint32)h) << 16);
}
__device__ __forceinline__ uint32 pk2(float a, float b) {
    return (uint32)f2bf(a) | ((uint32)f2bf(b) << 16);
}
__device__ __forceinline__ void upadd(uint32 p, float& a, float& b) {
    a += __uint_as_float(p << 16);
    b += __uint_as_float(p & 0xffff0000u);
}

// ---------------- CSR build ----------------
__global__ void k_deg(const int* __restrict__ dst, int* __restrict__ deg, int n)
{
    int i = blockIdx.x * 256 + threadIdx.x;
    if (i < n) atomicAdd(&deg[dst[i]], 1);
}

__global__ void k_gptr(const int* __restrict__ batch, int* __restrict__ gptr, int n)
{
    int i = blockIdx.x * 256 + threadIdx.x;
    if (i > n) return;
    if (i == 0) {
        int b0 = batch[0];
        for (int g = 0; g <= b0; ++g) gptr[g] = 0;
    } else if (i == n) {
        int bl = batch[n - 1];
        for (int g = bl + 1; g <= GG; ++g) gptr[g] = n;
    } else {
        int bp = batch[i - 1], bc = batch[i];
        for (int g = bp + 1; g <= bc; ++g) gptr[g] = i;
    }
}

__global__ __launch_bounds__(256) void k_scan1(const int* __restrict__ deg, int* __restrict__ bsum)
{
    __shared__ int sm[256];
    int base = blockIdx.x * 1024 + threadIdx.x * 4;
    int4 v = *(const int4*)(deg + base);
    sm[threadIdx.x] = v.x + v.y + v.z + v.w;
    __syncthreads();
    for (int off = 128; off > 0; off >>= 1) {
        if (threadIdx.x < off) sm[threadIdx.x] += sm[threadIdx.x + off];
        __syncthreads();
    }
    if (threadIdx.x == 0) bsum[blockIdx.x] = sm[0];
}

__global__ void k_scan2(const int* __restrict__ bsum, int* __restrict__ boff, int nb)
{
    if (threadIdx.x == 0) {
        int s = 0;
        for (int i = 0; i < nb; ++i) { boff[i] = s; s += bsum[i]; }
    }
}

__global__ __launch_bounds__(256) void k_scan3(const int* __restrict__ deg, const int* __restrict__ boff,
                                               int* __restrict__ ptr, int n)
{
    __shared__ int sm[256];
    int tid = threadIdx.x;
    int base = blockIdx.x * 1024 + tid * 4;
    int4 v = *(const int4*)(deg + base);
    int t = v.x + v.y + v.z + v.w;
    sm[tid] = t;
    __syncthreads();
    for (int off = 1; off < 256; off <<= 1) {
        int add = (tid >= off) ? sm[tid - off] : 0;
        __syncthreads();
        sm[tid] += add;
        __syncthreads();
    }
    int ex = boff[blockIdx.x] + sm[tid] - t;
    int pr0 = ex, pr1 = ex + v.x, pr2 = pr1 + v.y, pr3 = pr2 + v.z;
    int prs[4] = {pr0, pr1, pr2, pr3};
    for (int j = 0; j < 4; ++j) {
        int idx = base + j;
        if (idx <= n) ptr[idx] = prs[j];
    }
}

__global__ void k_gcur(const int* __restrict__ ptr, int* __restrict__ gcur)
{
    int i = blockIdx.x * 256 + threadIdx.x;
    if (i < NBK) gcur[i] = ptr[i * 256];
}

// phase A: bin edges by 256-node bucket with LDS staging, contiguous flush
__global__ __launch_bounds__(256) void kp_a(const int* __restrict__ src, const int* __restrict__ dst,
                                            int* __restrict__ gcur, uint32* __restrict__ binned)
{
    __shared__ int cnt[NBK];
    __shared__ int pref[NBK];
    __shared__ int gbase[NBK];
    __shared__ int scanA[512];
    __shared__ int scanB[512];
    __shared__ uint32 staged[EPB];
    __shared__ ushort sbk[EPB];
    const int t = threadIdx.x;
    const int e0 = blockIdx.x * EPB;
    const int nv = min(EPB, EE - e0);

    for (int i = t; i < NBK; i += 256) cnt[i] = 0;
    __syncthreads();
    for (int i = t; i < nv; i += 256)
        atomicAdd(&cnt[dst[e0 + i] >> 8], 1);
    __syncthreads();
    // scan (Hillis-Steele over 512)
    for (int i = t; i < 512; i += 256) scanA[i] = (i < NBK) ? cnt[i] : 0;
    __syncthreads();
    int* pa = scanA; int* pb = scanB;
    for (int off = 1; off < 512; off <<= 1) {
        for (int i = t; i < 512; i += 256)
            pb[i] = pa[i] + (i >= off ? pa[i - off] : 0);
        __syncthreads();
        int* tmp = pa; pa = pb; pb = tmp;
    }
    for (int i = t; i < NBK; i += 256) pref[i] = (i == 0) ? 0 : pa[i - 1];
    __syncthreads();
    // reserve global space, turn cnt into running cursor
    for (int i = t; i < NBK; i += 256) {
        gbase[i] = atomicAdd(&gcur[i], cnt[i]);
        cnt[i] = pref[i];
    }
    __syncthreads();
    // place into LDS
    for (int i = t; i < nv; i += 256) {
        int d = dst[e0 + i];
        int s = src[e0 + i];
        int b = d >> 8;
        int r = atomicAdd(&cnt[b], 1);
        staged[r] = (uint32)s | ((uint32)(d & 255) << 17);
        sbk[r] = (ushort)b;
    }
    __syncthreads();
    // flush contiguous runs
    for (int i = t; i < nv; i += 256) {
        int b = sbk[i];
        binned[gbase[b] + (i - pref[b])] = staged[i];
    }
}

// phase B: exact per-node placement within one bucket
__global__ __launch_bounds__(256) void kp_b(const uint32* __restrict__ binned,
                                            const int* __restrict__ ptr,
                                            int* __restrict__ csr)
{
    __shared__ int cur[256];
    const int b = blockIdx.x;
    const int n0 = b * 256;
    const int t = threadIdx.x;
    if (n0 + t < NN) cur[t] = ptr[n0 + t];
    __syncthreads();
    const int rs = ptr[n0];
    const int re = ptr[min(n0 + 256, NN)];
    for (int i = rs + t; i < re; i += 256) {
        uint32 rec = binned[i];
        int s = rec & 0x1FFFF;
        int dl = rec >> 17;
        int p = atomicAdd(&cur[dl], 1);
        csr[p] = s;
    }
}

// ---------------- conversions ----------------
__global__ void k_f2bf8(const float* __restrict__ in, ushort* __restrict__ out, int n8)
{
    int i = blockIdx.x * 256 + threadIdx.x;
    if (i >= n8) return;
    float4 a = ((const float4*)in)[i * 2];
    float4 b = ((const float4*)in)[i * 2 + 1];
    uint4 o;
    o.x = pk2(a.x, a.y); o.y = pk2(a.z, a.w);
    o.z = pk2(b.x, b.y); o.w = pk2(b.z, b.w);
    ((uint4*)out)[i] = o;
}

// all weight transposes W[K][N] fp32 -> WT[N][K] bf16 in one launch
struct WtJobs {
    const float* W[8];
    ushort* WT[8];
    int K[8], N[8], end[8];
};
__global__ __launch_bounds__(256) void k_wt_all(WtJobs jb)
{
    __shared__ float tl[32][33];
    int id = blockIdx.x;
    int j = 0;
    while (id >= jb.end[j]) ++j;
    int base = (j == 0) ? 0 : jb.end[j - 1];
    int local = id - base;
    const int K = jb.K[j], N = jb.N[j];
    const float* W = jb.W[j];
    ushort* WT = jb.WT[j];
    int nbk = K >> 5;
    int k0 = (local % nbk) * 32, n0 = (local / nbk) * 32;
    int tx = threadIdx.x & 31, ty = threadIdx.x >> 5;
#pragma unroll
    for (int q = 0; q < 4; ++q)
        tl[ty * 4 + q][tx] = W[(size_t)(k0 + ty * 4 + q) * N + n0 + tx];
    __syncthreads();
#pragma unroll
    for (int q = 0; q < 4; ++q)
        WT[(size_t)(n0 + ty * 4 + q) * K + k0 + tx] = f2bf(tl[tx][ty * 4 + q]);
}

// build head A: [512][6656] bf16 = concat(pool512 fp32, fp fp32)
__global__ void k_prep_head(const float* __restrict__ pool, const float* __restrict__ fp,
                            ushort* __restrict__ Ab)
{
    int i = blockIdx.x * 256 + threadIdx.x;       // chunk of 8
    if (i >= GG * RD / 8) return;
    int g = i / (RD / 8);
    int c = (i % (RD / 8)) * 8;
    const float* s = (c < 512) ? pool + (size_t)g * 512 + c
                               : fp + (size_t)g * FPD + (c - 512);
    float4 a = *(const float4*)s;
    float4 b = *(const float4*)(s + 4);
    uint4 o;
    o.x = pk2(a.x, a.y); o.y = pk2(a.z, a.w);
    o.z = pk2(b.x, b.y); o.w = pk2(b.z, b.w);
    ((uint4*)Ab)[i] = o;
}

// ---------------- aggregation (bf16 in/out, fp32 accum) ----------------
template<int D>
__global__ __launch_bounds__(256) void k_aggrb(const ushort* __restrict__ X,
                                               const int* __restrict__ ptr,
                                               const int* __restrict__ csr,
                                               ushort* __restrict__ out, int n_nodes)
{
    constexpr int SL = D / 8;          // lanes per node
    constexpr int NPB = 256 / SL;
    int sl = threadIdx.x % SL, ln = threadIdx.x / SL;
    int n = blockIdx.x * NPB + ln;
    if (n >= n_nodes) return;
    const uint4* Xv = (const uint4*)X;
    float a0 = 0, a1 = 0, a2 = 0, a3 = 0, a4 = 0, a5 = 0, a6 = 0, a7 = 0;
    uint4 v = Xv[(size_t)n * SL + sl];
    upadd(v.x, a0, a1); upadd(v.y, a2, a3); upadd(v.z, a4, a5); upadd(v.w, a6, a7);
    int e0 = ptr[n], e1 = ptr[n + 1];
    for (int e = e0; e < e1; ++e) {
        int s = csr[e];
        v = Xv[(size_t)s * SL + sl];
        upadd(v.x, a0, a1); upadd(v.y, a2, a3); upadd(v.z, a4, a5); upadd(v.w, a6, a7);
    }
    uint4 o;
    o.x = pk2(a0, a1); o.y = pk2(a2, a3); o.z = pk2(a4, a5); o.w = pk2(a6, a7);
    ((uint4*)out)[(size_t)n * SL + sl] = o;
}

// ---------------- fused 2-layer conv MLP ----------------
// H[M][DOUT] = relu(bn(relu(A@W1 + b1) @ W2 + b2))
// block = BROWS rows, 8 waves arranged WM x (8/WM); layer1 tile kept in LDS.
template<int KIN, int DMID, int DOUT, int BROWS, int WM>
__global__ __launch_bounds__(512) void k_conv(
    const ushort* __restrict__ A, const ushort* __restrict__ W1T, const float* __restrict__ b1,
    const ushort* __restrict__ W2T, const float* __restrict__ b2,
    const float* __restrict__ bng, const float* __restrict__ bnb,
    ushort* __restrict__ H, int M)
{
    constexpr int WN  = 8 / WM;
    constexpr int NF1 = DMID / WN / 16;   // 2
    constexpr int NF2 = DOUT / WN / 16;   // 2
    constexpr int MF  = BROWS / WM / 16;  // 4
    constexpr int LDK = DMID + 8;
    __shared__ ushort h1t[BROWS][LDK];

    const int t = threadIdx.x;
    const int lane = t & 63, w = t >> 6;
    const int wm = w / WN, wn = w % WN;
    const int fr = lane & 15, fq = lane >> 4;
    const long row0 = (long)blockIdx.x * BROWS + wm * (MF * 16);

    // ---- layer 1 (direct-reg MFMA) ----
    const ushort* ap[MF];
#pragma unroll
    for (int m = 0; m < MF; ++m) {
        long r = row0 + m * 16 + fr;
        if (r >= M) r = M - 1;
        ap[m] = A + r * KIN + fq * 8;
    }
    const ushort* b1p[NF1];
#pragma unroll
    for (int n = 0; n < NF1; ++n)
        b1p[n] = W1T + (size_t)(wn * (NF1 * 16) + n * 16 + fr) * KIN + fq * 8;

    f32x4 acc1[MF][NF1];
#pragma unroll
    for (int m = 0; m < MF; ++m)
#pragma unroll
        for (int n = 0; n < NF1; ++n)
            acc1[m][n] = (f32x4){0.f, 0.f, 0.f, 0.f};

#pragma unroll
    for (int ks = 0; ks < KIN / 32; ++ks) {
        bf16x8 fa[MF], fb[NF1];
#pragma unroll
        for (int m = 0; m < MF; ++m) fa[m] = *(const bf16x8*)(ap[m] + ks * 32);
#pragma unroll
        for (int n = 0; n < NF1; ++n) fb[n] = *(const bf16x8*)(b1p[n] + ks * 32);
#pragma unroll
        for (int n = 0; n < NF1; ++n)
#pragma unroll
            for (int m = 0; m < MF; ++m)
                acc1[m][n] = __builtin_amdgcn_mfma_f32_16x16x32_bf16(fa[m], fb[n], acc1[m][n], 0, 0, 0);
    }
    // bias + relu -> LDS tile
#pragma unroll
    for (int n = 0; n < NF1; ++n) {
        int col = wn * (NF1 * 16) + n * 16 + fr;
        float bi = b1[col];
#pragma unroll
        for (int m = 0; m < MF; ++m) {
            int rl = wm * (MF * 16) + m * 16 + fq * 4;
#pragma unroll
            for (int r = 0; r < 4; ++r)
                h1t[rl + r][col] = f2bf(fmaxf(acc1[m][n][r] + bi, 0.f));
        }
    }
    __syncthreads();

    // ---- layer 2 (A from LDS, B from L2) ----
    const ushort* b2p[NF2];
#pragma unroll
    for (int n = 0; n < NF2; ++n)
        b2p[n] = W2T + (size_t)(wn * (NF2 * 16) + n * 16 + fr) * DMID + fq * 8;

    f32x4 acc2[MF][NF2];
#pragma unroll
    for (int m = 0; m < MF; ++m)
#pragma unroll
        for (int n = 0; n < NF2; ++n)
            acc2[m][n] = (f32x4){0.f, 0.f, 0.f, 0.f};

#pragma unroll
    for (int ks = 0; ks < DMID / 32; ++ks) {
        bf16x8 fa[MF], fb[NF2];
#pragma unroll
        for (int m = 0; m < MF; ++m)
            fa[m] = *(const bf16x8*)&h1t[wm * (MF * 16) + m * 16 + fr][ks * 32 + fq * 8];
#pragma unroll
        for (int n = 0; n < NF2; ++n) fb[n] = *(const bf16x8*)(b2p[n] + ks * 32);
#pragma unroll
        for (int n = 0; n < NF2; ++n)
#pragma unroll
            for (int m = 0; m < MF; ++m)
                acc2[m][n] = __builtin_amdgcn_mfma_f32_16x16x32_bf16(fa[m], fb[n], acc2[m][n], 0, 0, 0);
    }
    // epilogue: bias + BN + relu -> bf16
#pragma unroll
    for (int n = 0; n < NF2; ++n) {
        int col = wn * (NF2 * 16) + n * 16 + fr;
        float bi = b2[col];
        float g = bng[col] * BN_SCALE, bb = bnb[col];
#pragma unroll
        for (int m = 0; m < MF; ++m) {
            long rbase = row0 + m * 16 + fq * 4;
#pragma unroll
            for (int r = 0; r < 4; ++r) {
                long row = rbase + r;
                if (row < M)
                    H[row * DOUT + col] = f2bf(fmaxf((acc2[m][n][r] + bi) * g + bb, 0.f));
            }
        }
    }
}

// ---------------- direct-to-register MFMA GEMM (head / out3) ----------------
template<int GRID, int EPI>
__global__ __launch_bounds__(256) void k_rgemm(
    const ushort* __restrict__ A, const ushort* __restrict__ BT,
    void* __restrict__ Cout, int M, int K, int NOUT, int kchunk)
{
    int id = blockIdx.x;
    int bx, by, bz;
    if constexpr (GRID == 1) {
        int vid = (id & 7) * (4 * 26 * HZ / 8) + (id >> 3);  // chunk 104 per XCD
        bx = vid & 3; int cz = vid >> 2; by = cz % 26; bz = cz / 26;
    } else {
        bx = id & 3; by = 0; bz = id >> 2;
    }
    const int t = threadIdx.x;
    const int lane = t & 63, w = t >> 6;
    const int wm = w >> 1, wn = w & 1;
    const int fr = lane & 15, fq = lane >> 4;
    const long row0 = (long)bx * 128 + wm * 64;
    const int col0 = by * 128 + wn * 64;
    const int kb = bz * kchunk;
    const int nks = kchunk >> 5;

    const ushort* ap[4];
    const ushort* bp[4];
#pragma unroll
    for (int m = 0; m < 4; ++m) {
        long r = row0 + m * 16 + fr;
        if (r >= M) r = M - 1;
        ap[m] = A + r * (long)K + kb + fq * 8;
    }
#pragma unroll
    for (int n = 0; n < 4; ++n)
        bp[n] = BT + (size_t)(col0 + n * 16 + fr) * K + kb + fq * 8;

    f32x4 acc[4][4];
#pragma unroll
    for (int m = 0; m < 4; ++m)
#pragma unroll
        for (int n = 0; n < 4; ++n)
            acc[m][n] = (f32x4){0.f, 0.f, 0.f, 0.f};

    bf16x8 aS0[4], bS0[4], aS1[4], bS1[4];

#define LOADSET(sA, sB, KS)                                            \
    {                                                                  \
        int _o = (KS) * 32;                                            \
        _Pragma("unroll")                                              \
        for (int j = 0; j < 4; ++j) sA[j] = *(const bf16x8*)(ap[j] + _o); \
        _Pragma("unroll")                                              \
        for (int j = 0; j < 4; ++j) sB[j] = *(const bf16x8*)(bp[j] + _o); \
    }
#define MFMASET(sA, sB)                                                \
    _Pragma("unroll")                                                  \
    for (int n = 0; n < 4; ++n)                                        \
        _Pragma("unroll")                                              \
        for (int m = 0; m < 4; ++m)                                    \
            acc[m][n] = __builtin_amdgcn_mfma_f32_16x16x32_bf16(sA[m], sB[n], acc[m][n], 0, 0, 0);

    LOADSET(aS0, bS0, 0)
    for (int ks = 0; ks < nks; ks += 2) {
        LOADSET(aS1, bS1, ks + 1)
        MFMASET(aS0, bS0)
        if (ks + 2 < nks) LOADSET(aS0, bS0, ks + 2)
        MFMASET(aS1, bS1)
    }
#undef LOADSET
#undef MFMASET

#pragma unroll
    for (int n = 0; n < 4; ++n) {
        int col = col0 + n * 16 + fr;
#pragma unroll
        for (int m = 0; m < 4; ++m) {
            long rbase = row0 + m * 16 + fq * 4;
#pragma unroll
            for (int r = 0; r < 4; ++r) {
                long row = rbase + r;
                if (row < M) {
                    if constexpr (EPI == 2)
                        ((float*)Cout)[(size_t)bz * M * NOUT + row * NOUT + col] = acc[m][n][r];
                    else
                        ((ushort*)Cout)[(size_t)bz * M * NOUT + row * NOUT + col] = f2bf(acc[m][n][r]);
                }
            }
        }
    }
}

// ---------------- split-K reductions ----------------
__global__ void k_red_head(const ushort* __restrict__ P, const float* __restrict__ bias,
                           const float* __restrict__ g, const float* __restrict__ b,
                           ushort* __restrict__ O)
{
    int i = blockIdx.x * 256 + threadIdx.x;     // 512*3328
    int col = i % RH;
    float s = 0.f;
#pragma unroll
    for (int z = 0; z < HZ; ++z) s += bf2f(P[(size_t)z * (GG * RH) + i]);
    float o = (s + bias[col]) * (g[col] * BN_SCALE) + b[col];
    O[i] = f2bf(fmaxf(o, 0.f));
}

__global__ void k_red_out(const float* __restrict__ P, const float* __restrict__ bias,
                          float* __restrict__ O)
{
    int i = blockIdx.x * 256 + threadIdx.x;     // 512*128
    float s = 0.f;
#pragma unroll
    for (int z = 0; z < OZ; ++z) s += P[(size_t)z * (GG * NC) + i];
    O[i] = s + bias[i & (NC - 1)];
}

// ---------------- per-graph pooling ----------------
template<int D>
__global__ __launch_bounds__(256) void k_poolb(const ushort* __restrict__ H,
                                               const int* __restrict__ gptr,
                                               float* __restrict__ pool512, int colOff)
{
    constexpr int SL = D / 8;
    constexpr int SUB = 256 / SL;
    __shared__ float red[SUB][D];
    int sl = threadIdx.x % SL, su = threadIdx.x / SL;
    int g = blockIdx.x;
    int n0 = gptr[g], n1 = gptr[g + 1];
    float a0 = 0, a1 = 0, a2 = 0, a3 = 0, a4 = 0, a5 = 0, a6 = 0, a7 = 0;
    const uint4* Hv = (const uint4*)H;
    for (int n = n0 + su; n < n1; n += SUB) {
        uint4 v = Hv[(size_t)n * SL + sl];
        upadd(v.x, a0, a1); upadd(v.y, a2, a3); upadd(v.z, a4, a5); upadd(v.w, a6, a7);
    }
    float* rr = &red[su][sl * 8];
    rr[0] = a0; rr[1] = a1; rr[2] = a2; rr[3] = a3;
    rr[4] = a4; rr[5] = a5; rr[6] = a6; rr[7] = a7;
    __syncthreads();
    for (int c = threadIdx.x; c < D; c += 256) {
        float s = 0.f;
#pragma unroll
        for (int u = 0; u < SUB; ++u) s += red[u][c];
        pool512[(size_t)g * 512 + colOff + c] = s;
    }
}

// ---------------- launch ----------------
extern "C" void kernel_launch(void* const* d_in, const int* in_sizes, int n_in,
                              void* d_out, int out_size, void* d_ws, size_t ws_size,
                              hipStream_t stream)
{
    const float* x     = (const float*)d_in[0];
    const int*   ei    = (const int*)d_in[1];
    const int*   src   = ei;
    const int*   dst   = ei + EE;
    const int*   batch = (const int*)d_in[2];
    const float* fp    = (const float*)d_in[3];
    const float* c1w1  = (const float*)d_in[4];
    const float* c1b1  = (const float*)d_in[5];
    const float* c1w2  = (const float*)d_in[6];
    const float* c1b2  = (const float*)d_in[7];
    const float* c2w1  = (const float*)d_in[8];
    const float* c2b1  = (const float*)d_in[9];
    const float* c2w2  = (const float*)d_in[10];
    const float* c2b2  = (const float*)d_in[11];
    const float* c3w1  = (const float*)d_in[12];
    const float* c3b1  = (const float*)d_in[13];
    const float* c3w2  = (const float*)d_in[14];
    const float* c3b2  = (const float*)d_in[15];
    const float* bn1g  = (const float*)d_in[16];
    const float* bn1b  = (const float*)d_in[17];
    const float* bn2g  = (const float*)d_in[18];
    const float* bn2b  = (const float*)d_in[19];
    const float* bn3g  = (const float*)d_in[20];
    const float* bn3b  = (const float*)d_in[21];
    const float* o1w   = (const float*)d_in[22];
    const float* o1b   = (const float*)d_in[23];
    const float* obng  = (const float*)d_in[24];
    const float* obnb  = (const float*)d_in[25];
    const float* o3w   = (const float*)d_in[26];
    const float* o3b   = (const float*)d_in[27];
    float* out = (float*)d_out;

    char* ws = (char*)d_ws;
    size_t off = 0;
    auto alloc = [&](size_t bytes) {
        size_t r = off;
        off = (off + bytes + 255) & ~(size_t)255;
        return (void*)(ws + r);
    };
    ushort* aggbuf = (ushort*)alloc((size_t)NN * 256 * 2);
    ushort* h3     = (ushort*)alloc((size_t)NN * 256 * 2);
    ushort* xbf    = (ushort*)alloc((size_t)NN * 64 * 2);
    ushort* h1     = (ushort*)alloc((size_t)NN * 128 * 2);
    ushort* h2     = (ushort*)alloc((size_t)NN * 128 * 2);
    ushort* headA  = (ushort*)alloc((size_t)GG * RD * 2);
    ushort* hmid   = (ushort*)alloc((size_t)GG * RH * 2);
    ushort* wtc1a  = (ushort*)alloc((size_t)128 * 64 * 2);
    ushort* wtc1b  = (ushort*)alloc((size_t)128 * 128 * 2);
    ushort* wtc2a  = (ushort*)alloc((size_t)128 * 128 * 2);
    ushort* wtc2b  = (ushort*)alloc((size_t)128 * 128 * 2);
    ushort* wtc3a  = (ushort*)alloc((size_t)256 * 128 * 2);
    ushort* wtc3b  = (ushort*)alloc((size_t)256 * 256 * 2);
    ushort* wtH    = (ushort*)alloc((size_t)RH * RD * 2);
    ushort* wtO    = (ushort*)alloc((size_t)NC * RH * 2);
    float* pool512 = (float*)alloc((size_t)GG * 512 * 4);
    ushort* partH  = (ushort*)alloc((size_t)HZ * GG * RH * 2);
    float*  partO  = (float*)alloc((size_t)OZ * GG * NC * 4);
    uint32* binned = (uint32*)alloc((size_t)EE * 4);
    int* deg    = (int*)alloc((size_t)NP_PAD * 4);
    int* ptr    = (int*)alloc((size_t)(NN + 1) * 4);
    int* gcur   = (int*)alloc((size_t)NBK * 4);
    int* bsum   = (int*)alloc((size_t)NB_SCAN * 4);
    int* boff   = (int*)alloc((size_t)NB_SCAN * 4);
    int* gptr   = (int*)alloc((size_t)(GG + 1) * 4);
    int* csr    = (int*)alloc((size_t)EE * 4);
    (void)ws_size; (void)in_sizes; (void)n_in; (void)out_size;

    // ---- CSR + graph boundaries ----
    hipMemsetAsync(deg, 0, (size_t)NP_PAD * 4, stream);
    k_deg<<<(EE + 255) / 256, 256, 0, stream>>>(dst, deg, EE);
    k_gptr<<<(NN + 256) / 256, 256, 0, stream>>>(batch, gptr, NN);
    k_scan1<<<NB_SCAN, 256, 0, stream>>>(deg, bsum);
    k_scan2<<<1, 64, 0, stream>>>(bsum, boff, NB_SCAN);
    k_scan3<<<NB_SCAN, 256, 0, stream>>>(deg, boff, ptr, NN);
    k_gcur<<<(NBK + 255) / 256, 256, 0, stream>>>(ptr, gcur);
    kp_a<<<(EE + EPB - 1) / EPB, 256, 0, stream>>>(src, dst, gcur, binned);
    kp_b<<<NBK, 256, 0, stream>>>(binned, ptr, csr);

    // ---- one-time conversions ----
    k_f2bf8<<<(NN * 64 / 8 + 255) / 256, 256, 0, stream>>>(x, xbf, NN * 64 / 8);
    {
        WtJobs jb;
        const float* Ws[8]  = {c1w1, c1w2, c2w1, c2w2, c3w1, c3w2, o1w, o3w};
        ushort* WTs[8]      = {wtc1a, wtc1b, wtc2a, wtc2b, wtc3a, wtc3b, wtH, wtO};
        int Ks[8]           = {64, 128, 128, 128, 128, 256, RD, RH};
        int Ns[8]           = {128, 128, 128, 128, 256, 256, RH, NC};
        int cum = 0;
        for (int j = 0; j < 8; ++j) {
            jb.W[j] = Ws[j]; jb.WT[j] = WTs[j]; jb.K[j] = Ks[j]; jb.N[j] = Ns[j];
            cum += (Ks[j] >> 5) * (Ns[j] >> 5);
            jb.end[j] = cum;
        }
        k_wt_all<<<cum, 256, 0, stream>>>(jb);
    }

    const int MT = (NN + 127) / 128;  // 782

    // ---- conv1 ----
    k_aggrb<64><<<(NN + 31) / 32, 256, 0, stream>>>(xbf, ptr, csr, aggbuf, NN);
    k_conv<64, 128, 128, 128, 2><<<MT, 512, 0, stream>>>(
        aggbuf, wtc1a, c1b1, wtc1b, c1b2, bn1g, bn1b, h1, NN);
    k_poolb<128><<<GG, 256, 0, stream>>>(h1, gptr, pool512, 0);

    // ---- conv2 ----
    k_aggrb<128><<<(NN + 15) / 16, 256, 0, stream>>>(h1, ptr, csr, aggbuf, NN);
    k_conv<128, 128, 128, 128, 2><<<MT, 512, 0, stream>>>(
        aggbuf, wtc2a, c2b1, wtc2b, c2b2, bn2g, bn2b, h2, NN);
    k_poolb<128><<<GG, 256, 0, stream>>>(h2, gptr, pool512, DH);

    // ---- conv3 ----
    k_aggrb<128><<<(NN + 15) / 16, 256, 0, stream>>>(h2, ptr, csr, aggbuf, NN);
    k_conv<128, 256, 256, 64, 1><<<MT * 2, 512, 0, stream>>>(
        aggbuf, wtc3a, c3b1, wtc3b, c3b2, bn3g, bn3b, h3, NN);
    k_poolb<256><<<GG, 256, 0, stream>>>(h3, gptr, pool512, 2 * DH);

    // ---- head: split-K=8, XCD-chunked, bf16 partials ----
    k_prep_head<<<(GG * RD / 8 + 255) / 256, 256, 0, stream>>>(pool512, fp, headA);
    k_rgemm<1, 3><<<4 * 26 * HZ, 256, 0, stream>>>(headA, wtH, partH, GG, RD, RH, RD / HZ);
    k_red_head<<<(GG * RH) / 256, 256, 0, stream>>>(partH, o1b, obng, obnb, hmid);

    // ---- out3: split-K=26, f32 partials ----
    k_rgemm<2, 2><<<4 * OZ, 256, 0, stream>>>(hmid, wtO, partO, GG, RH, NC, RH / OZ);
    k_red_out<<<(GG * NC) / 256, 256, 0, stream>>>(partO, o3b, out);
}